// Round 13
// baseline (120.260 us; speedup 1.0000x reference)
//
#include <hip/hip_runtime.h>
#include <hip/hip_bf16.h>

#define DEVI __device__ __forceinline__

constexpr int B_ = 32, CI = 128, CM = 256, H_ = 32, W_ = 32;
constexpr int S_ = 1024, NB = 100;
constexpr float LAMF = 0.7f, ILAMF = 0.3f, SCALEF = 3.0f;
// chunked channel-last activation layouts: [b][ch/8][pos][8ch]
constexpr size_t XSZ = (size_t)32 * 16 * 1156 * 8;   // per-ab xpad elems (34x34 pos)
constexpr size_t XBS = (size_t)16 * 1156 * 8;        // per-b stride
constexpr size_t CSZ = (size_t)32 * 32 * 324 * 8;    // per-ab cpad elems (18x18 pos)
constexpr size_t CBS = (size_t)32 * 324 * 8;

typedef short bf8 __attribute__((ext_vector_type(8)));
typedef float f4 __attribute__((ext_vector_type(4)));
typedef unsigned short u16;
typedef unsigned int u32;

struct alignas(8) us4 { u16 v[4]; };
struct alignas(16) us8 { u16 v[8]; };

// deconv tap order, parity-grouped: par0{0,2,6,8} par3{4} | par1{1,7} par2{3,5}
__device__ __constant__ int TAPD9c[9] = {0, 2, 6, 8, 1, 7, 3, 5, 4};

DEVI u16 f2bf(float f) {
    unsigned u = __builtin_bit_cast(unsigned, f);
    u += 0x7FFFu + ((u >> 16) & 1u);
    return (u16)(u >> 16);
}
DEVI float bf2f(u16 h) {
    unsigned u = ((unsigned)h) << 16;
    return __builtin_bit_cast(float, u);
}

DEVI void gll16(const void* g, void* l) {
    __builtin_amdgcn_global_load_lds(
        (const __attribute__((address_space(1))) u32*)g,
        (__attribute__((address_space(3))) u32*)l, 16, 0, 0);
}

DEVI float waveSum(float v) {
#pragma unroll
    for (int off = 32; off > 0; off >>= 1) v += __shfl_down(v, off, 64);
    return v;
}
DEVI float blockSum256(float v, float* lds4) {
    v = waveSum(v);
    int wid = threadIdx.x >> 6, lane = threadIdx.x & 63;
    __syncthreads();
    if (lane == 0) lds4[wid] = v;
    __syncthreads();
    return lds4[0] + lds4[1] + lds4[2] + lds4[3];
}
DEVI float blockSum128(float v, float* lds2) {
    v = waveSum(v);
    int wid = threadIdx.x >> 6, lane = threadIdx.x & 63;
    __syncthreads();
    if (lane == 0) lds2[wid] = v;
    __syncthreads();
    return lds2[0] + lds2[1];
}
DEVI float blockMax128(float v, float* lds2) {
#pragma unroll
    for (int off = 32; off > 0; off >>= 1) v = fmaxf(v, __shfl_down(v, off, 64));
    int wid = threadIdx.x >> 6, lane = threadIdx.x & 63;
    __syncthreads();
    if (lane == 0) lds2[wid] = v;
    __syncthreads();
    return fmaxf(lds2[0], lds2[1]);
}

// ---- weight prep: staging-linear k-slot-major layouts (unchanged from R8) ----
__global__ __launch_bounds__(256) void k_prep_w(const float* __restrict__ We,
                                                const float* __restrict__ Wf,
                                                const float* __restrict__ Wd,
                                                u16* __restrict__ A1p,
                                                u16* __restrict__ A2p,
                                                u16* __restrict__ A3p) {
    int i = blockIdx.x * 256 + threadIdx.x;  // 294912
    {
        int e = i & 7, s = (i >> 3) & 511, j = i >> 12;  // j 0..71
        int Mt = j / 36, kc = j - Mt * 36;
        int tap = kc >> 2, cq = kc & 3;
        int q = s >> 7, m = s & 127;
        int oc = Mt * 128 + m, ch = cq * 32 + q * 8 + e;
        A1p[i] = f2bf(We[((size_t)oc * CI + ch) * 9 + tap]);
    }
    {
        int e = i & 7, s = (i >> 3) & 511, kc = i >> 12;  // 0..71
        int tapi = kc >> 3, cq = kc & 7;
        int q = s >> 7, m = s & 127;
        int ch = cq * 32 + q * 8 + e;
        A2p[i] = f2bf(Wf[((size_t)m * CM + ch) * 9 + tapi]);
        A3p[i] = f2bf(Wd[((size_t)m * CM + ch) * 9 + TAPD9c[tapi]]);
    }
}

// ---- proxies ----
__global__ __launch_bounds__(128) void k_prox(const float* __restrict__ P,
                                              float* __restrict__ PnT,
                                              float* __restrict__ pn2) {
    __shared__ float lds2[2];
    int k = blockIdx.x, t = threadIdx.x;
    float v = P[k * CI + t];
    float ss = blockSum128(v * v, lds2);
    float sc = SCALEF / fmaxf(sqrtf(ss), 1e-12f);
    float pv = v * sc;
    PnT[t * NB + k] = pv;
    float s2 = blockSum128(pv * pv, lds2);
    if (t == 0) pn2[k] = s2;
}

// ---- zero the padding rings of xpad and cpad ----
__global__ __launch_bounds__(256) void k_ring(u16* __restrict__ xpad, u16* __restrict__ cpad) {
    int b = blockIdx.x, ab = blockIdx.y, t = threadIdx.x;
    u16* xp = xpad + (size_t)ab * XSZ + (size_t)b * XBS;
    u16* cp = cpad + (size_t)ab * CSZ + (size_t)b * CBS;
    us8 z = {};
    for (int i = t; i < 132 * 16; i += 256) {
        int cc = i / 132, rp = i - cc * 132;
        int pos;
        if (rp < 68) pos = (rp < 34) ? (32 * 34 + rp) : (33 * 34 + rp - 34);
        else { int r2 = rp - 68; pos = (r2 >> 1) * 34 + 32 + (r2 & 1); }
        *(us8*)(xp + ((size_t)cc * 1156 + pos) * 8) = z;
    }
    for (int i = t; i < 68 * 32; i += 256) {
        int cc = i / 68, rp = i - cc * 68;
        int pos;
        if (rp < 36) pos = (rp < 18) ? rp : (17 * 18 + rp - 18);
        else { int r2 = rp - 36; pos = (1 + (r2 >> 1)) * 18 + ((r2 & 1) ? 17 : 0); }
        *(us8*)(cp + ((size_t)cc * 324 + pos) * 8) = z;
    }
}

// ---- fused: x -> bf16 chunked xpad + invd (LDS-only) + meanx/meanfl ----
__global__ __launch_bounds__(256) void k_xpose(const float* __restrict__ xa,
                                               const float* __restrict__ xb,
                                               u16* __restrict__ xpad,
                                               float* __restrict__ meanbuf) {
    __shared__ float ldsx[128][64];   // 32KB
    __shared__ float sred[256];
    __shared__ float sinv[64];
    int b = blockIdx.x, yg = blockIdx.y, ab = blockIdx.z;
    int t = threadIdx.x;
    const float* x = (ab ? xb : xa) + (size_t)b * CI * S_ + yg * 64;
    int c4 = t >> 6, p = t & 63;
    for (int c0 = 0; c0 < 32; ++c0) {
        int c = c0 * 4 + c4;
        ldsx[c][p] = x[(size_t)c * S_ + p];
    }
    __syncthreads();
    int qc = t >> 6;
    int y = yg * 2 + (p >> 5), xcol = p & 31;
    u16* ox = xpad + (size_t)ab * XSZ + (size_t)b * XBS;
    float ss = 0.f;
#pragma unroll
    for (int c8 = 0; c8 < 4; ++c8) {
        int cb = qc * 32 + c8 * 8;
        int cc = cb >> 3;
        us8 pk;
#pragma unroll
        for (int j = 0; j < 8; ++j) {
            float v = ldsx[cb + j][p];
            ss = fmaf(v, v, ss);
            pk.v[j] = f2bf(v);
        }
        *(us8*)(ox + ((size_t)cc * 1156 + y * 34 + xcol) * 8) = pk;
    }
    sred[t] = ss;
    __syncthreads();
    if (t < 64) {
        float s = sred[t] + sred[t + 64] + sred[t + 128] + sred[t + 192];
        sinv[t] = 1.f / fmaxf(sqrtf(s), 1e-12f);
    }
    __syncthreads();
    int c = t >> 1, h = t & 1;
    float sx = 0.f, sf = 0.f;
    for (int i = 0; i < 32; ++i) {
        int p2 = h * 32 + ((i + c) & 31);
        float v = ldsx[c][p2];
        sx += v;
        sf = fmaf(v, sinv[p2], sf);
    }
    sx += __shfl_xor(sx, 1, 64);
    sf += __shfl_xor(sf, 1, 64);
    if (!(t & 1)) {
        atomicAdd(&meanbuf[(size_t)ab * 4096 + b * 128 + c], sx * (1.f / 1024.f));
        atomicAdd(&meanbuf[8192 + (size_t)ab * 4096 + b * 128 + c], sf * (1.f / 1024.f));
    }
}

// ---- conv1: K-64 steps (18), tile M128 x N64, LDS dbuf (unchanged from R8) ----
__global__ __launch_bounds__(256, 2) void k_conv1g(const u16* __restrict__ XC,
                                                   const u16* __restrict__ A1p,
                                                   u16* __restrict__ CC) {
    __shared__ u16 sA[2][8192];
    __shared__ u16 sB[2][4096];
    int t = threadIdx.x, l = t & 63, l15 = l & 15, lq = l >> 4, w = t >> 6;
    int wm = w & 1, wn = w >> 1;
    int Nt = blockIdx.x, b = blockIdx.y;
    int ab = blockIdx.z & 1, Mt = blockIdx.z >> 1;
    const u16* xc = XC + (size_t)ab * XSZ + (size_t)b * XBS;
    const u16* Ag = A1p + (size_t)Mt * (36 * 4096);
    int bpos0 = (8 * Nt + 2 * (l >> 4)) * 34 + 2 * (l & 15);
    const int po1[9] = {0, 1, 2, 34, 35, 36, 68, 69, 70};

    auto stageA = [&](int buf, int kcA) {
        const u16* ga = Ag + (size_t)kcA * 4096 + t * 8;
        u16* da = &sA[buf][w * 512];
#pragma unroll
        for (int i = 0; i < 4; ++i) gll16(ga + i * 2048, da + i * 2048);
    };
    auto stageB = [&](int buf, int po, int s) {
#pragma unroll
        for (int i = 0; i < 2; ++i) {
            int ks = i * 4 + w;
            gll16(xc + ((size_t)(s * 8 + ks) * 1156 + bpos0 + po) * 8,
                  &sB[buf][(size_t)ks * 512]);
        }
    };

    f4 acc[4][2] = {};
    stageA(0, 0);
    stageB(0, 0, 0);
    int cur = 0;
#pragma unroll
    for (int ti = 0; ti < 9; ++ti) {
        const int po = po1[ti];
        const int poN = (ti < 8) ? po1[ti + 1] : 0;
#pragma unroll 1
        for (int s = 0; s < 2; ++s) {
            __syncthreads();
            bool last = (ti == 8) && (s == 1);
            if (!last) {
                int tin = (s < 1) ? ti : ti + 1;
                int sn = (s < 1) ? 1 : 0;
                stageA(cur ^ 1, tin * 4 + sn * 2);
                stageB(cur ^ 1, (s < 1) ? po : poN, sn);
            }
            const u16* As = sA[cur];
            const u16* Bs = sB[cur];
#pragma unroll
            for (int kc2 = 0; kc2 < 2; ++kc2) {
                bf8 af[4], bv[2];
#pragma unroll
                for (int mf = 0; mf < 4; ++mf)
                    af[mf] = *(const bf8*)(As + ((kc2 * 4 + lq) * 128 + wm * 64 + mf * 16 + l15) * 8);
#pragma unroll
                for (int nf = 0; nf < 2; ++nf)
                    bv[nf] = *(const bf8*)(Bs + ((kc2 * 4 + lq) * 64 + wn * 32 + nf * 16 + l15) * 8);
#pragma unroll
                for (int mf = 0; mf < 4; ++mf)
#pragma unroll
                    for (int nf = 0; nf < 2; ++nf)
                        acc[mf][nf] = __builtin_amdgcn_mfma_f32_16x16x32_bf16(af[mf], bv[nf], acc[mf][nf], 0, 0, 0);
            }
            cur ^= 1;
        }
    }
    u16* cb = CC + (size_t)ab * CSZ + (size_t)b * CBS;
#pragma unroll
    for (int mf = 0; mf < 4; ++mf) {
        int mc = Mt * 128 + wm * 64 + mf * 16 + lq * 4;
#pragma unroll
        for (int nf = 0; nf < 2; ++nf) {
            int nl = wn * 32 + nf * 16 + l15;
            int oh = Nt * 4 + (nl >> 4), ow = nl & 15;
            int posO = (1 + oh) * 18 + 1 + ow;
            us4 pk;
#pragma unroll
            for (int r = 0; r < 4; ++r) pk.v[r] = f2bf(fmaxf(acc[mf][nf][r], 0.f));
            *(us4*)(cb + ((size_t)(mc >> 3) * 324 + posO) * 8 + (mc & 7)) = pk;
        }
    }
}

// ---- k_cde8: resident B-slab + streamed A with T4 counted-vmcnt pipeline ----
// Triple-buffered A (3x16KB), loads issued 2 steps ahead; per step:
// issue 4 gll16 -> s_waitcnt vmcnt(8) -> raw s_barrier (no drain) -> compute.
// Slab restage at h-boundary uses full __syncthreads (ledger resets to 0, safe).
// grid (2 Nt, 32 b, 6: type*2+ab)

#define COMPUTE(ACC)                                                           \
    {                                                                          \
        const u16* As = sA + ib3 * 8192;                                       \
        _Pragma("unroll") for (int kc2 = 0; kc2 < 2; ++kc2) {                  \
            bf8 af[4], bv[4];                                                  \
            _Pragma("unroll") for (int mf = 0; mf < 4; ++mf)                   \
                af[mf] = *(const bf8*)(As + kc2 * 4096 + aq + mf * 128);       \
            _Pragma("unroll") for (int nf = 0; nf < 4; ++nf)                   \
                bv[nf] = *(const bf8*)(sS + ((2 * sub + kc2) * 720 + bq +      \
                                             (nf + oy) * 18 + ox) * 8);        \
            _Pragma("unroll") for (int mf = 0; mf < 4; ++mf)                   \
                _Pragma("unroll") for (int nf = 0; nf < 4; ++nf)               \
                    ACC[mf][nf] = __builtin_amdgcn_mfma_f32_16x16x32_bf16(     \
                        af[mf], bv[nf], ACC[mf][nf], 0, 0, 0);                 \
        }                                                                      \
    }

#define PIPE_SYNC(NSTEP)                                                       \
    if (s + 2 < (NSTEP)) asm volatile("s_waitcnt vmcnt(8)" ::: "memory");      \
    else if (s + 1 < (NSTEP)) asm volatile("s_waitcnt vmcnt(4)" ::: "memory"); \
    else asm volatile("s_waitcnt vmcnt(0)" ::: "memory");                      \
    __builtin_amdgcn_s_barrier();                                              \
    __builtin_amdgcn_sched_barrier(0);

#define FLUSH(ACC, PY, PX)                                                     \
    _Pragma("unroll") for (int mf = 0; mf < 4; ++mf) {                         \
        int mc = wm * 64 + mf * 16 + lq * 4;                                   \
        const u16* xrow = xq + (size_t)(mc >> 3) * 1156 * 8 + (mc & 7);        \
        _Pragma("unroll") for (int nf = 0; nf < 4; ++nf) {                     \
            int n = wn * 64 + nf * 16 + l15;                                   \
            int oh = 8 * Nt + (n >> 4), ow = n & 15;                           \
            int Y = 2 * oh + (PY), X = 2 * ow + (PX);                          \
            us4 xv = *(const us4*)(xrow + (size_t)(Y * 34 + X) * 8);           \
            _Pragma("unroll") for (int r = 0; r < 4; ++r) {                    \
                float d = ACC[mf][nf][r] - bf2f(xv.v[r]);                      \
                ss = fmaf(d, d, ss);                                           \
            }                                                                  \
        }                                                                      \
    }

__global__ __launch_bounds__(256, 2) void k_cde8(const u16* __restrict__ CC,
                                                 const u16* __restrict__ A2p,
                                                 const u16* __restrict__ A3p,
                                                 const u16* __restrict__ XC,
                                                 float* __restrict__ feats,
                                                 float* __restrict__ pr) {
    __shared__ u16 sS[23040];      // [ccL16][pos 10x18][8e] = 45KB resident slab
    __shared__ u16 sA[3 * 8192];   // A triple-buffer 3x16KB
    __shared__ float lds4[4];
    int t = threadIdx.x, l = t & 63, l15 = l & 15, lq = l >> 4, w = t >> 6;
    int wm = w & 1, wn = w >> 1;
    int Nt = blockIdx.x, b = blockIdx.y;
    int ab = blockIdx.z & 1, type = blockIdx.z >> 1;
    const u16* cbb = CC + (size_t)ab * CSZ + (size_t)b * CBS;
    const u16* xq = XC + (size_t)ab * XSZ + (size_t)b * XBS;
    const u16* Ag = type ? A3p : A2p;
    int r0 = 8 * Nt;
    int aq = (lq * 128 + wm * 64 + l15) * 8;
    int bq = lq * 180 + wn * 72 + l15;

    auto stageA = [&](int buf, int kcA) {   // 2 kc chunks = 16KB (4 gll16/wave)
        const u16* ga = Ag + (size_t)kcA * 4096 + t * 8;
        u16* da = &sA[buf * 8192 + w * 512];
#pragma unroll
        for (int i = 0; i < 4; ++i) gll16(ga + i * 2048, da + i * 2048);
    };
    auto stage_slab = [&](int h) {          // reg-staged copy, 16 chunks x 180 us8
        if (t < 180) {
#pragma unroll 1
            for (int ccL = 0; ccL < 16; ++ccL) {
                int cc = h * 16 + ccL;
                us8 v = *(const us8*)(cbb + ((size_t)cc * 324 + r0 * 18 + t) * 8);
                *(us8*)(sS + ((size_t)ccL * 180 + t) * 8) = v;
            }
        }
    };

    float ss = 0.f;
    if (type == 0) {
        // conv2: 36 steps; kcA(s) = (rr>>1)*8 + h*4 + (rr&1)*2, rr=s%18, h=s/18
        f4 acc[4][4] = {};
        stageA(0, 0);
        stageA(1, 2);
        stage_slab(0);
        __syncthreads();
#pragma unroll 1
        for (int s = 0; s < 36; ++s) {
            if (s == 18) { __syncthreads(); stage_slab(1); __syncthreads(); }
            if (s + 2 < 36) {
                int s2 = s + 2, h2 = s2 / 18, rr2 = s2 - h2 * 18;
                stageA(s2 % 3, (rr2 >> 1) * 8 + h2 * 4 + (rr2 & 1) * 2);
            }
            PIPE_SYNC(36);
            int ib3 = s % 3;
            int rr = (s < 18) ? s : s - 18;
            int sub = rr & 1, ti = rr >> 1;
            int oy = ti / 3, ox = ti - oy * 3;
            COMPUTE(acc);
        }
        float* fo = feats + ((size_t)ab * B_ + b) * CI;
#pragma unroll
        for (int mf = 0; mf < 4; ++mf)
#pragma unroll
            for (int r = 0; r < 4; ++r) {
                float v = 0.f;
#pragma unroll
                for (int nf = 0; nf < 4; ++nf) v += fmaxf(acc[mf][nf][r], 0.f);
                v += __shfl_xor(v, 1, 64);
                v += __shfl_xor(v, 2, 64);
                v += __shfl_xor(v, 4, 64);
                v += __shfl_xor(v, 8, 64);
                if (l15 == 0)
                    atomicAdd(fo + wm * 64 + mf * 16 + lq * 4 + r, v * (1.f / 256.f));
            }
    } else if (type == 1) {
        // deconv par{0,3}: 20 steps; rr=s%10: rr<8 -> accP taps{0,2,6,8}, rr>=8 -> accQ tap{4}
        f4 accP[4][4] = {}, accQ[4][4] = {};
        stageA(0, 0);
        stageA(1, 2);
        stage_slab(0);
        __syncthreads();
#pragma unroll 1
        for (int s = 0; s < 20; ++s) {
            if (s == 10) { __syncthreads(); stage_slab(1); __syncthreads(); }
            if (s + 2 < 20) {
                int s2 = s + 2, h2 = s2 / 10, rr2 = s2 - h2 * 10;
                int tapi2 = (rr2 < 8) ? (rr2 >> 1) : 8;
                int sub2 = (rr2 < 8) ? (rr2 & 1) : (rr2 - 8);
                stageA(s2 % 3, tapi2 * 8 + h2 * 4 + sub2 * 2);
            }
            PIPE_SYNC(20);
            int ib3 = s % 3;
            int rr = (s < 10) ? s : s - 10;
            if (rr < 8) {
                int sub = rr & 1, tp = rr >> 1;
                int oy = tp >> 1, ox = tp & 1;
                COMPUTE(accP);
            } else {
                int sub = rr - 8, oy = 1, ox = 1;
                COMPUTE(accQ);
            }
        }
        FLUSH(accP, 0, 0);
        FLUSH(accQ, 1, 1);
        ss = blockSum256(ss, lds4);
        if (t == 0) atomicAdd(pr + ab, ss);
    } else {
        // deconv par{1,2}: 16 steps; rr=s%8: rr<4 -> accP taps{1,7}, rr>=4 -> accQ taps{3,5}
        f4 accP[4][4] = {}, accQ[4][4] = {};
        stageA(0, 32);
        stageA(1, 34);
        stage_slab(0);
        __syncthreads();
#pragma unroll 1
        for (int s = 0; s < 16; ++s) {
            if (s == 8) { __syncthreads(); stage_slab(1); __syncthreads(); }
            if (s + 2 < 16) {
                int s2 = s + 2, h2 = s2 >> 3, rr2 = s2 & 7;
                stageA(s2 % 3, (4 + (rr2 >> 1)) * 8 + h2 * 4 + (rr2 & 1) * 2);
            }
            PIPE_SYNC(16);
            int ib3 = s % 3;
            int rr = s & 7;
            if (rr < 4) {
                int sub = rr & 1, oy = rr >> 1, ox = 1;
                COMPUTE(accP);
            } else {
                int sub = rr & 1, oy = 1, ox = (rr >> 1) - 2;
                COMPUTE(accQ);
            }
        }
        FLUSH(accP, 0, 1);
        FLUSH(accQ, 1, 0);
        ss = blockSum256(ss, lds4);
        if (t == 0) atomicAdd(pr + ab, ss);
    }
}

#undef COMPUTE
#undef PIPE_SYNC
#undef FLUSH

// ---- metric (mix fused: sets 2/3 from meanbuf; Sinkhorn dead code) ----
__global__ __launch_bounds__(128) void k_metric(const float* __restrict__ feats,
                                                const float* __restrict__ meanbuf,
                                                const float* __restrict__ PnT,
                                                const float* __restrict__ pn2,
                                                const int* __restrict__ la,
                                                const int* __restrict__ lb,
                                                float* __restrict__ mo) {
    __shared__ float lds2[2];
    __shared__ float xs[128];
    int blk = blockIdx.x;
    int t = threadIdx.x;
    int b = blk & 31;
    float xv;
    if (blk < 64) xv = feats[(size_t)blk * CI + t];
    else if (blk < 96) xv = LAMF * meanbuf[b * 128 + t] + ILAMF * meanbuf[12288 + b * 128 + t];
    else xv = LAMF * meanbuf[4096 + b * 128 + t] + ILAMF * meanbuf[8192 + b * 128 + t];
    float ssq = blockSum128(xv * xv, lds2);
    float sc = SCALEF / fmaxf(sqrtf(ssq), 1e-12f);
    float xn = xv * sc;
    xs[t] = xn;
    float xn2 = blockSum128(xn * xn, lds2);
    bool active = (t < NB);
    float Dk = 1e30f;
    if (active) {
        float dot = 0.f;
#pragma unroll 8
        for (int e = 0; e < CI; ++e) dot = fmaf(xs[e], PnT[e * NB + t], dot);
        Dk = xn2 + pn2[t] - 2.f * dot;
    }
    float z = active ? -Dk : -1e30f;
    float m = blockMax128(z, lds2);
    float e = active ? expf(z - m) : 0.f;
    float se = blockSum128(e, lds2);
    float lse = m + logf(se);
    if (t == 0) mo[blk * 3 + 0] = lse;
    int A = la[b], Bb = lb[b];
    if (t == A) mo[blk * 3 + 1] = Dk;
    if (t == Bb) mo[blk * 3 + 2] = Dk;
}

__global__ __launch_bounds__(128) void k_final(const float* __restrict__ pr,
                                               const float* __restrict__ mo,
                                               float* __restrict__ out) {
    __shared__ float mla[4], mlb[4];
    int t = threadIdx.x;
    const float* m = mo + t * 3;
    float ula = m[0] + m[1];
    float ulb = m[0] + m[2];
#pragma unroll
    for (int off = 16; off > 0; off >>= 1) {
        ula += __shfl_down(ula, off, 32);
        ulb += __shfl_down(ulb, off, 32);
    }
    if ((t & 31) == 0) { mla[t >> 5] = ula * (1.f / 32.f); mlb[t >> 5] = ulb * (1.f / 32.f); }
    __syncthreads();
    if (t == 0) {
        float lxa = pr[0] * (1.f / 4194304.f);
        float lxb = pr[1] * (1.f / 4194304.f);
        float lca = mla[0];
        float lcb = mlb[1];
        float lcma = LAMF * mla[2] + ILAMF * mlb[2];
        float lcmb = LAMF * mlb[3] + ILAMF * mla[3];
        out[0] = lxa + lxb + lca + lcb + lcma + lcmb;
        out[1] = lxa; out[2] = lxb; out[3] = lca; out[4] = lcb; out[5] = lcma; out[6] = lcmb;
    }
}

extern "C" void kernel_launch(void* const* d_in, const int* in_sizes, int n_in,
                              void* d_out, int out_size, void* d_ws, size_t ws_size,
                              hipStream_t stream) {
    const float* xa = (const float*)d_in[0];
    const float* xb = (const float*)d_in[1];
    const int* la = (const int*)d_in[2];
    const int* lb = (const int*)d_in[3];
    const float* P = (const float*)d_in[4];
    const float* We = (const float*)d_in[5];
    const float* Wf = (const float*)d_in[6];
    const float* Wd = (const float*)d_in[7];

    char* w = (char*)d_ws;
    const size_t XPAD_B = XSZ * 2 * sizeof(u16);
    const size_t CPAD_B = CSZ * 2 * sizeof(u16);
    const size_t AW_B = (size_t)294912 * 2;
    u16* xpad = (u16*)w;                 w += XPAD_B;
    u16* cpad = (u16*)w;                 w += CPAD_B;
    u16* A1p = (u16*)w;                  w += AW_B;
    u16* A2p = (u16*)w;                  w += AW_B;
    u16* A3p = (u16*)w;                  w += AW_B;
    float* PnT = (float*)w;              w += 12800 * 4;
    float* pn2 = (float*)w;              w += 128 * 4;
    float* feats = (float*)w;            w += 8192 * 4;    // [2 ab][32][128]
    float* meanbuf = (float*)w;          w += 16384 * 4;   // [2 kind][2 ab][32][128]
    float* pr = (float*)w;               w += 16 * 4;
    float* mo = (float*)w;               w += 384 * 4;
    float* out = (float*)d_out;

    hipMemsetAsync(feats, 0, (8192 + 16384 + 16) * sizeof(float), stream);

    k_prep_w<<<1152, 256, 0, stream>>>(We, Wf, Wd, A1p, A2p, A3p);
    k_prox<<<NB, 128, 0, stream>>>(P, PnT, pn2);
    k_ring<<<dim3(32, 2), 256, 0, stream>>>(xpad, cpad);
    k_xpose<<<dim3(32, 16, 2), 256, 0, stream>>>(xa, xb, xpad, meanbuf);
    k_conv1g<<<dim3(4, 32, 4), 256, 0, stream>>>(xpad, A1p, cpad);
    k_cde8<<<dim3(2, 32, 6), 256, 0, stream>>>(cpad, A2p, A3p, xpad, feats, pr);
    k_metric<<<128, 128, 0, stream>>>(feats, meanbuf, PnT, pn2, la, lb, mo);
    k_final<<<1, 128, 0, stream>>>(pr, mo, out);
}

// Round 14
// 107.380 us; speedup vs baseline: 1.1199x; 1.1199x over previous
//
#include <hip/hip_runtime.h>
#include <hip/hip_bf16.h>

#define DEVI __device__ __forceinline__

constexpr int B_ = 32, CI = 128, CM = 256, H_ = 32, W_ = 32;
constexpr int S_ = 1024, NB = 100;
constexpr float LAMF = 0.7f, ILAMF = 0.3f, SCALEF = 3.0f;
// chunked channel-last activation layouts: [b][ch/8][pos][8ch]
constexpr size_t XSZ = (size_t)32 * 16 * 1156 * 8;   // per-ab xpad elems (34x34 pos)
constexpr size_t XBS = (size_t)16 * 1156 * 8;        // per-b stride
constexpr size_t CSZ = (size_t)32 * 32 * 324 * 8;    // per-ab cpad elems (18x18 pos)
constexpr size_t CBS = (size_t)32 * 324 * 8;

typedef short bf8 __attribute__((ext_vector_type(8)));
typedef float f4 __attribute__((ext_vector_type(4)));
typedef float f16v __attribute__((ext_vector_type(16)));
typedef unsigned short u16;
typedef unsigned int u32;

struct alignas(8) us4 { u16 v[4]; };
struct alignas(16) us8 { u16 v[8]; };

// deconv tap order, parity-grouped: par0{0,2,6,8} par3{4} | par1{1,7} par2{3,5}
__device__ __constant__ int TAPD9c[9] = {0, 2, 6, 8, 1, 7, 3, 5, 4};

DEVI u16 f2bf(float f) {
    unsigned u = __builtin_bit_cast(unsigned, f);
    u += 0x7FFFu + ((u >> 16) & 1u);
    return (u16)(u >> 16);
}
DEVI float bf2f(u16 h) {
    unsigned u = ((unsigned)h) << 16;
    return __builtin_bit_cast(float, u);
}

DEVI void gll16(const void* g, void* l) {
    __builtin_amdgcn_global_load_lds(
        (const __attribute__((address_space(1))) u32*)g,
        (__attribute__((address_space(3))) u32*)l, 16, 0, 0);
}

DEVI float waveSum(float v) {
#pragma unroll
    for (int off = 32; off > 0; off >>= 1) v += __shfl_down(v, off, 64);
    return v;
}
DEVI float blockSum256(float v, float* lds4) {
    v = waveSum(v);
    int wid = threadIdx.x >> 6, lane = threadIdx.x & 63;
    __syncthreads();
    if (lane == 0) lds4[wid] = v;
    __syncthreads();
    return lds4[0] + lds4[1] + lds4[2] + lds4[3];
}
DEVI float blockSum128(float v, float* lds2) {
    v = waveSum(v);
    int wid = threadIdx.x >> 6, lane = threadIdx.x & 63;
    __syncthreads();
    if (lane == 0) lds2[wid] = v;
    __syncthreads();
    return lds2[0] + lds2[1];
}
DEVI float blockMax128(float v, float* lds2) {
#pragma unroll
    for (int off = 32; off > 0; off >>= 1) v = fmaxf(v, __shfl_down(v, off, 64));
    int wid = threadIdx.x >> 6, lane = threadIdx.x & 63;
    __syncthreads();
    if (lane == 0) lds2[wid] = v;
    __syncthreads();
    return fmaxf(lds2[0], lds2[1]);
}

// ---- weight prep: staging-linear k-slot-major layouts (unchanged from R8) ----
__global__ __launch_bounds__(256) void k_prep_w(const float* __restrict__ We,
                                                const float* __restrict__ Wf,
                                                const float* __restrict__ Wd,
                                                u16* __restrict__ A1p,
                                                u16* __restrict__ A2p,
                                                u16* __restrict__ A3p) {
    int i = blockIdx.x * 256 + threadIdx.x;  // 294912
    {
        int e = i & 7, s = (i >> 3) & 511, j = i >> 12;  // j 0..71
        int Mt = j / 36, kc = j - Mt * 36;
        int tap = kc >> 2, cq = kc & 3;
        int q = s >> 7, m = s & 127;
        int oc = Mt * 128 + m, ch = cq * 32 + q * 8 + e;
        A1p[i] = f2bf(We[((size_t)oc * CI + ch) * 9 + tap]);
    }
    {
        int e = i & 7, s = (i >> 3) & 511, kc = i >> 12;  // 0..71
        int tapi = kc >> 3, cq = kc & 7;
        int q = s >> 7, m = s & 127;
        int ch = cq * 32 + q * 8 + e;
        A2p[i] = f2bf(Wf[((size_t)m * CM + ch) * 9 + tapi]);
        A3p[i] = f2bf(Wd[((size_t)m * CM + ch) * 9 + TAPD9c[tapi]]);
    }
}

// ---- proxies ----
__global__ __launch_bounds__(128) void k_prox(const float* __restrict__ P,
                                              float* __restrict__ PnT,
                                              float* __restrict__ pn2) {
    __shared__ float lds2[2];
    int k = blockIdx.x, t = threadIdx.x;
    float v = P[k * CI + t];
    float ss = blockSum128(v * v, lds2);
    float sc = SCALEF / fmaxf(sqrtf(ss), 1e-12f);
    float pv = v * sc;
    PnT[t * NB + k] = pv;
    float s2 = blockSum128(pv * pv, lds2);
    if (t == 0) pn2[k] = s2;
}

// ---- zero the padding rings of xpad and cpad ----
__global__ __launch_bounds__(256) void k_ring(u16* __restrict__ xpad, u16* __restrict__ cpad) {
    int b = blockIdx.x, ab = blockIdx.y, t = threadIdx.x;
    u16* xp = xpad + (size_t)ab * XSZ + (size_t)b * XBS;
    u16* cp = cpad + (size_t)ab * CSZ + (size_t)b * CBS;
    us8 z = {};
    for (int i = t; i < 132 * 16; i += 256) {
        int cc = i / 132, rp = i - cc * 132;
        int pos;
        if (rp < 68) pos = (rp < 34) ? (32 * 34 + rp) : (33 * 34 + rp - 34);
        else { int r2 = rp - 68; pos = (r2 >> 1) * 34 + 32 + (r2 & 1); }
        *(us8*)(xp + ((size_t)cc * 1156 + pos) * 8) = z;
    }
    for (int i = t; i < 68 * 32; i += 256) {
        int cc = i / 68, rp = i - cc * 68;
        int pos;
        if (rp < 36) pos = (rp < 18) ? rp : (17 * 18 + rp - 18);
        else { int r2 = rp - 36; pos = (1 + (r2 >> 1)) * 18 + ((r2 & 1) ? 17 : 0); }
        *(us8*)(cp + ((size_t)cc * 324 + pos) * 8) = z;
    }
}

// ---- fused: x -> bf16 chunked xpad + invd (LDS-only) + meanx/meanfl ----
__global__ __launch_bounds__(256) void k_xpose(const float* __restrict__ xa,
                                               const float* __restrict__ xb,
                                               u16* __restrict__ xpad,
                                               float* __restrict__ meanbuf) {
    __shared__ float ldsx[128][64];   // 32KB
    __shared__ float sred[256];
    __shared__ float sinv[64];
    int b = blockIdx.x, yg = blockIdx.y, ab = blockIdx.z;
    int t = threadIdx.x;
    const float* x = (ab ? xb : xa) + (size_t)b * CI * S_ + yg * 64;
    int c4 = t >> 6, p = t & 63;
    for (int c0 = 0; c0 < 32; ++c0) {
        int c = c0 * 4 + c4;
        ldsx[c][p] = x[(size_t)c * S_ + p];
    }
    __syncthreads();
    int qc = t >> 6;
    int y = yg * 2 + (p >> 5), xcol = p & 31;
    u16* ox = xpad + (size_t)ab * XSZ + (size_t)b * XBS;
    float ss = 0.f;
#pragma unroll
    for (int c8 = 0; c8 < 4; ++c8) {
        int cb = qc * 32 + c8 * 8;
        int cc = cb >> 3;
        us8 pk;
#pragma unroll
        for (int j = 0; j < 8; ++j) {
            float v = ldsx[cb + j][p];
            ss = fmaf(v, v, ss);
            pk.v[j] = f2bf(v);
        }
        *(us8*)(ox + ((size_t)cc * 1156 + y * 34 + xcol) * 8) = pk;
    }
    sred[t] = ss;
    __syncthreads();
    if (t < 64) {
        float s = sred[t] + sred[t + 64] + sred[t + 128] + sred[t + 192];
        sinv[t] = 1.f / fmaxf(sqrtf(s), 1e-12f);
    }
    __syncthreads();
    int c = t >> 1, h = t & 1;
    float sx = 0.f, sf = 0.f;
    for (int i = 0; i < 32; ++i) {
        int p2 = h * 32 + ((i + c) & 31);
        float v = ldsx[c][p2];
        sx += v;
        sf = fmaf(v, sinv[p2], sf);
    }
    sx += __shfl_xor(sx, 1, 64);
    sf += __shfl_xor(sf, 1, 64);
    if (!(t & 1)) {
        atomicAdd(&meanbuf[(size_t)ab * 4096 + b * 128 + c], sx * (1.f / 1024.f));
        atomicAdd(&meanbuf[8192 + (size_t)ab * 4096 + b * 128 + c], sf * (1.f / 1024.f));
    }
}

// ---- conv1: K-64 steps (18), tile M128 x N64, LDS dbuf (unchanged from R8) ----
__global__ __launch_bounds__(256, 2) void k_conv1g(const u16* __restrict__ XC,
                                                   const u16* __restrict__ A1p,
                                                   u16* __restrict__ CC) {
    __shared__ u16 sA[2][8192];
    __shared__ u16 sB[2][4096];
    int t = threadIdx.x, l = t & 63, l15 = l & 15, lq = l >> 4, w = t >> 6;
    int wm = w & 1, wn = w >> 1;
    int Nt = blockIdx.x, b = blockIdx.y;
    int ab = blockIdx.z & 1, Mt = blockIdx.z >> 1;
    const u16* xc = XC + (size_t)ab * XSZ + (size_t)b * XBS;
    const u16* Ag = A1p + (size_t)Mt * (36 * 4096);
    int bpos0 = (8 * Nt + 2 * (l >> 4)) * 34 + 2 * (l & 15);
    const int po1[9] = {0, 1, 2, 34, 35, 36, 68, 69, 70};

    auto stageA = [&](int buf, int kcA) {
        const u16* ga = Ag + (size_t)kcA * 4096 + t * 8;
        u16* da = &sA[buf][w * 512];
#pragma unroll
        for (int i = 0; i < 4; ++i) gll16(ga + i * 2048, da + i * 2048);
    };
    auto stageB = [&](int buf, int po, int s) {
#pragma unroll
        for (int i = 0; i < 2; ++i) {
            int ks = i * 4 + w;
            gll16(xc + ((size_t)(s * 8 + ks) * 1156 + bpos0 + po) * 8,
                  &sB[buf][(size_t)ks * 512]);
        }
    };

    f4 acc[4][2] = {};
    stageA(0, 0);
    stageB(0, 0, 0);
    int cur = 0;
#pragma unroll
    for (int ti = 0; ti < 9; ++ti) {
        const int po = po1[ti];
        const int poN = (ti < 8) ? po1[ti + 1] : 0;
#pragma unroll 1
        for (int s = 0; s < 2; ++s) {
            __syncthreads();
            bool last = (ti == 8) && (s == 1);
            if (!last) {
                int tin = (s < 1) ? ti : ti + 1;
                int sn = (s < 1) ? 1 : 0;
                stageA(cur ^ 1, tin * 4 + sn * 2);
                stageB(cur ^ 1, (s < 1) ? po : poN, sn);
            }
            const u16* As = sA[cur];
            const u16* Bs = sB[cur];
#pragma unroll
            for (int kc2 = 0; kc2 < 2; ++kc2) {
                bf8 af[4], bv[2];
#pragma unroll
                for (int mf = 0; mf < 4; ++mf)
                    af[mf] = *(const bf8*)(As + ((kc2 * 4 + lq) * 128 + wm * 64 + mf * 16 + l15) * 8);
#pragma unroll
                for (int nf = 0; nf < 2; ++nf)
                    bv[nf] = *(const bf8*)(Bs + ((kc2 * 4 + lq) * 64 + wn * 32 + nf * 16 + l15) * 8);
#pragma unroll
                for (int mf = 0; mf < 4; ++mf)
#pragma unroll
                    for (int nf = 0; nf < 2; ++nf)
                        acc[mf][nf] = __builtin_amdgcn_mfma_f32_16x16x32_bf16(af[mf], bv[nf], acc[mf][nf], 0, 0, 0);
            }
            cur ^= 1;
        }
    }
    u16* cb = CC + (size_t)ab * CSZ + (size_t)b * CBS;
#pragma unroll
    for (int mf = 0; mf < 4; ++mf) {
        int mc = Mt * 128 + wm * 64 + mf * 16 + lq * 4;
#pragma unroll
        for (int nf = 0; nf < 2; ++nf) {
            int nl = wn * 32 + nf * 16 + l15;
            int oh = Nt * 4 + (nl >> 4), ow = nl & 15;
            int posO = (1 + oh) * 18 + 1 + ow;
            us4 pk;
#pragma unroll
            for (int r = 0; r < 4; ++r) pk.v[r] = f2bf(fmaxf(acc[mf][nf][r], 0.f));
            *(us4*)(cb + ((size_t)(mc >> 3) * 324 + posO) * 8 + (mc & 7)) = pk;
        }
    }
}

// ---- k_cde9: resident B-slab + streamed A, 32x32x16 MFMA (half the LDS reads) ----
// Sync skeleton identical to R11's k_cde7 (proven). Wave tile M64xN64 = 2x2 frags
// of 32; per K-64 step: 16 ds_read_b128 + 16 mfma_32x32x16.
// grid (2 Nt, 32 b, 6: type*2+ab)

#define KSTEP(ACC, SUBV, KYV, KXV, HN, KCAN)                                        \
    {                                                                               \
        __syncthreads();                                                            \
        if (HN) stageA(cur ^ 1, (KCAN));                                            \
        const u16* As = sA[cur];                                                    \
        _Pragma("unroll") for (int kc2 = 0; kc2 < 2; ++kc2) {                       \
            _Pragma("unroll") for (int j = 0; j < 2; ++j) {                         \
                bf8 a0 = *(const bf8*)(As + kc2 * 4096 + j * 2048 + aBase);         \
                bf8 a1 = *(const bf8*)(As + kc2 * 4096 + j * 2048 + aBase + 256);   \
                const u16* bp = sS + ((2 * (SUBV) + kc2) * 720 + j * 360) * 8 + bBase; \
                bf8 b0 = *(const bf8*)(bp + (((KYV)) * 18 + (KXV)) * 8);            \
                bf8 b1 = *(const bf8*)(bp + (((KYV) + 2) * 18 + (KXV)) * 8);        \
                ACC[0][0] = __builtin_amdgcn_mfma_f32_32x32x16_bf16(a0, b0, ACC[0][0], 0, 0, 0); \
                ACC[0][1] = __builtin_amdgcn_mfma_f32_32x32x16_bf16(a0, b1, ACC[0][1], 0, 0, 0); \
                ACC[1][0] = __builtin_amdgcn_mfma_f32_32x32x16_bf16(a1, b0, ACC[1][0], 0, 0, 0); \
                ACC[1][1] = __builtin_amdgcn_mfma_f32_32x32x16_bf16(a1, b1, ACC[1][1], 0, 0, 0); \
            }                                                                       \
        }                                                                           \
        cur ^= 1;                                                                   \
    }

#define FLUSH(ACC, PY, PX)                                                          \
    _Pragma("unroll") for (int mf = 0; mf < 2; ++mf) {                              \
        _Pragma("unroll") for (int nf = 0; nf < 2; ++nf) {                          \
            int n = wn * 64 + nf * 32 + l31;                                        \
            int oh = 8 * Nt + (n >> 4), ow = n & 15;                                \
            int Y = 2 * oh + (PY), X = 2 * ow + (PX);                               \
            _Pragma("unroll") for (int rg = 0; rg < 4; ++rg) {                      \
                int mc = wm * 64 + mf * 32 + 8 * rg + 4 * lh;                       \
                us4 xv = *(const us4*)(xq + (size_t)(mc >> 3) * 1156 * 8 +          \
                                       (size_t)(Y * 34 + X) * 8 + (mc & 7));        \
                _Pragma("unroll") for (int r = 0; r < 4; ++r) {                     \
                    float d = ACC[mf][nf][rg * 4 + r] - bf2f(xv.v[r]);              \
                    ss = fmaf(d, d, ss);                                            \
                }                                                                   \
            }                                                                       \
        }                                                                           \
    }

__global__ __launch_bounds__(256, 2) void k_cde9(const u16* __restrict__ CC,
                                                 const u16* __restrict__ A2p,
                                                 const u16* __restrict__ A3p,
                                                 const u16* __restrict__ XC,
                                                 float* __restrict__ feats,
                                                 float* __restrict__ pr) {
    __shared__ u16 sS[23040];     // [ccL16][pos 10x18][8e] = 45KB resident slab
    __shared__ u16 sA[2][8192];   // A dbuf 2x16KB
    __shared__ float lds4[4];
    int t = threadIdx.x, l = t & 63, l31 = l & 31, lh = l >> 5, w = t >> 6;
    int wm = w & 1, wn = w >> 1;
    int Nt = blockIdx.x, b = blockIdx.y;
    int ab = blockIdx.z & 1, type = blockIdx.z >> 1;
    const u16* cbb = CC + (size_t)ab * CSZ + (size_t)b * CBS;
    const u16* xq = XC + (size_t)ab * XSZ + (size_t)b * XBS;
    const u16* Ag = type ? A3p : A2p;
    int r0 = 8 * Nt;
    int aBase = (lh * 128 + wm * 64 + l31) * 8;
    int bBase = (lh * 180 + (wn * 4 + (l31 >> 4)) * 18 + (l31 & 15)) * 8;

    auto stageA = [&](int buf, int kcA) {   // 2 chunks = 16KB contiguous
        const u16* ga = Ag + (size_t)kcA * 4096 + t * 8;
        u16* da = &sA[buf][w * 512];
#pragma unroll
        for (int i = 0; i < 4; ++i) gll16(ga + i * 2048, da + i * 2048);
    };
    auto stage_slab = [&](int h) {          // reg-staged copy, 16 chunks x 180 us8
        if (t < 180) {
#pragma unroll 1
            for (int ccL = 0; ccL < 16; ++ccL) {
                int cc = h * 16 + ccL;
                us8 v = *(const us8*)(cbb + ((size_t)cc * 324 + r0 * 18 + t) * 8);
                *(us8*)(sS + ((size_t)ccL * 180 + t) * 8) = v;
            }
        }
    };

    int cur = 0;
    float ss = 0.f;
    if (type == 0) {
        f16v acc[2][2] = {};
        stage_slab(0);
        stageA(0, 0);
#pragma unroll
        for (int h = 0; h < 2; ++h) {
            if (h == 1) { __syncthreads(); stage_slab(1); }
#pragma unroll 1
            for (int st = 0; st < 18; ++st) {
                int s = h * 18 + st;
                int ti = st >> 1, sub = st & 1;
                int ky = ti / 3, kx = ti - ky * 3;
                bool hn = s < 35;
                int s1 = hn ? s + 1 : 0;
                int h1 = s1 / 18, rr = s1 - h1 * 18;
                int kcan = (rr >> 1) * 8 + h1 * 4 + (rr & 1) * 2;
                KSTEP(acc, sub, ky, kx, hn, kcan);
            }
        }
        float* fo = feats + ((size_t)ab * B_ + b) * CI;
#pragma unroll
        for (int mf = 0; mf < 2; ++mf)
#pragma unroll
            for (int reg = 0; reg < 16; ++reg) {
                float v = fmaxf(acc[mf][0][reg], 0.f) + fmaxf(acc[mf][1][reg], 0.f);
                v += __shfl_xor(v, 1, 64);
                v += __shfl_xor(v, 2, 64);
                v += __shfl_xor(v, 4, 64);
                v += __shfl_xor(v, 8, 64);
                v += __shfl_xor(v, 16, 64);
                if (l31 == 0)
                    atomicAdd(fo + wm * 64 + mf * 32 + (reg & 3) + 8 * (reg >> 2) + 4 * lh,
                              v * (1.f / 256.f));
            }
    } else if (type == 1) {
        // taps {0,2,6,8} -> accP (par0), tap {4} -> accQ (par3)
        f16v accP[2][2] = {}, accQ[2][2] = {};
        stage_slab(0);
        stageA(0, 0);
#pragma unroll
        for (int h = 0; h < 2; ++h) {
            if (h == 1) { __syncthreads(); stage_slab(1); }
#pragma unroll 1
            for (int st = 0; st < 8; ++st) {
                int s = h * 10 + st;
                int ip = st >> 1, sub = st & 1;
                int dy = ip >> 1, dx = ip & 1;
                bool hn = s < 19;
                int s1 = hn ? s + 1 : 0;
                int h1 = s1 / 10, rr = s1 - h1 * 10;
                int tapi1 = (rr < 8) ? (rr >> 1) : 8;
                int sub1 = (rr < 8) ? (rr & 1) : (rr - 8);
                int kcan = tapi1 * 8 + h1 * 4 + sub1 * 2;
                KSTEP(accP, sub, dy, dx, hn, kcan);
            }
#pragma unroll 1
            for (int st = 0; st < 2; ++st) {
                int s = h * 10 + 8 + st;
                int sub = st;
                bool hn = s < 19;
                int s1 = hn ? s + 1 : 0;
                int h1 = s1 / 10, rr = s1 - h1 * 10;
                int tapi1 = (rr < 8) ? (rr >> 1) : 8;
                int sub1 = (rr < 8) ? (rr & 1) : (rr - 8);
                int kcan = tapi1 * 8 + h1 * 4 + sub1 * 2;
                KSTEP(accQ, sub, 1, 1, hn, kcan);
            }
        }
        FLUSH(accP, 0, 0);
        FLUSH(accQ, 1, 1);
        ss = blockSum256(ss, lds4);
        if (t == 0) atomicAdd(pr + ab, ss);
    } else {
        // tapi {4,5} = taps {1,7} -> accP (par1); tapi {6,7} = taps {3,5} -> accQ (par2)
        f16v accP[2][2] = {}, accQ[2][2] = {};
        stage_slab(0);
        stageA(0, 32);
#pragma unroll
        for (int h = 0; h < 2; ++h) {
            if (h == 1) { __syncthreads(); stage_slab(1); }
#pragma unroll 1
            for (int st = 0; st < 4; ++st) {
                int s = h * 8 + st;
                int ip = st >> 1, sub = st & 1;
                bool hn = s < 15;
                int s1 = hn ? s + 1 : 0;
                int h1 = s1 >> 3, rr = s1 & 7;
                int kcan = (4 + (rr >> 1)) * 8 + h1 * 4 + (rr & 1) * 2;
                KSTEP(accP, sub, ip, 1, hn, kcan);
            }
#pragma unroll 1
            for (int st = 0; st < 4; ++st) {
                int s = h * 8 + 4 + st;
                int iq = st >> 1, sub = st & 1;
                bool hn = s < 15;
                int s1 = hn ? s + 1 : 0;
                int h1 = s1 >> 3, rr = s1 & 7;
                int kcan = (4 + (rr >> 1)) * 8 + h1 * 4 + (rr & 1) * 2;
                KSTEP(accQ, sub, 1, iq, hn, kcan);
            }
        }
        FLUSH(accP, 0, 1);
        FLUSH(accQ, 1, 0);
        ss = blockSum256(ss, lds4);
        if (t == 0) atomicAdd(pr + ab, ss);
    }
}

#undef KSTEP
#undef FLUSH

// ---- metric (mix fused: sets 2/3 from meanbuf; Sinkhorn dead code) ----
__global__ __launch_bounds__(128) void k_metric(const float* __restrict__ feats,
                                                const float* __restrict__ meanbuf,
                                                const float* __restrict__ PnT,
                                                const float* __restrict__ pn2,
                                                const int* __restrict__ la,
                                                const int* __restrict__ lb,
                                                float* __restrict__ mo) {
    __shared__ float lds2[2];
    __shared__ float xs[128];
    int blk = blockIdx.x;
    int t = threadIdx.x;
    int b = blk & 31;
    float xv;
    if (blk < 64) xv = feats[(size_t)blk * CI + t];
    else if (blk < 96) xv = LAMF * meanbuf[b * 128 + t] + ILAMF * meanbuf[12288 + b * 128 + t];
    else xv = LAMF * meanbuf[4096 + b * 128 + t] + ILAMF * meanbuf[8192 + b * 128 + t];
    float ssq = blockSum128(xv * xv, lds2);
    float sc = SCALEF / fmaxf(sqrtf(ssq), 1e-12f);
    float xn = xv * sc;
    xs[t] = xn;
    float xn2 = blockSum128(xn * xn, lds2);
    bool active = (t < NB);
    float Dk = 1e30f;
    if (active) {
        float dot = 0.f;
#pragma unroll 8
        for (int e = 0; e < CI; ++e) dot = fmaf(xs[e], PnT[e * NB + t], dot);
        Dk = xn2 + pn2[t] - 2.f * dot;
    }
    float z = active ? -Dk : -1e30f;
    float m = blockMax128(z, lds2);
    float e = active ? expf(z - m) : 0.f;
    float se = blockSum128(e, lds2);
    float lse = m + logf(se);
    if (t == 0) mo[blk * 3 + 0] = lse;
    int A = la[b], Bb = lb[b];
    if (t == A) mo[blk * 3 + 1] = Dk;
    if (t == Bb) mo[blk * 3 + 2] = Dk;
}

__global__ __launch_bounds__(128) void k_final(const float* __restrict__ pr,
                                               const float* __restrict__ mo,
                                               float* __restrict__ out) {
    __shared__ float mla[4], mlb[4];
    int t = threadIdx.x;
    const float* m = mo + t * 3;
    float ula = m[0] + m[1];
    float ulb = m[0] + m[2];
#pragma unroll
    for (int off = 16; off > 0; off >>= 1) {
        ula += __shfl_down(ula, off, 32);
        ulb += __shfl_down(ulb, off, 32);
    }
    if ((t & 31) == 0) { mla[t >> 5] = ula * (1.f / 32.f); mlb[t >> 5] = ulb * (1.f / 32.f); }
    __syncthreads();
    if (t == 0) {
        float lxa = pr[0] * (1.f / 4194304.f);
        float lxb = pr[1] * (1.f / 4194304.f);
        float lca = mla[0];
        float lcb = mlb[1];
        float lcma = LAMF * mla[2] + ILAMF * mlb[2];
        float lcmb = LAMF * mlb[3] + ILAMF * mla[3];
        out[0] = lxa + lxb + lca + lcb + lcma + lcmb;
        out[1] = lxa; out[2] = lxb; out[3] = lca; out[4] = lcb; out[5] = lcmb - lcmb + lcma; out[6] = lcmb;
    }
}

extern "C" void kernel_launch(void* const* d_in, const int* in_sizes, int n_in,
                              void* d_out, int out_size, void* d_ws, size_t ws_size,
                              hipStream_t stream) {
    const float* xa = (const float*)d_in[0];
    const float* xb = (const float*)d_in[1];
    const int* la = (const int*)d_in[2];
    const int* lb = (const int*)d_in[3];
    const float* P = (const float*)d_in[4];
    const float* We = (const float*)d_in[5];
    const float* Wf = (const float*)d_in[6];
    const float* Wd = (const float*)d_in[7];

    char* w = (char*)d_ws;
    const size_t XPAD_B = XSZ * 2 * sizeof(u16);
    const size_t CPAD_B = CSZ * 2 * sizeof(u16);
    const size_t AW_B = (size_t)294912 * 2;
    u16* xpad = (u16*)w;                 w += XPAD_B;
    u16* cpad = (u16*)w;                 w += CPAD_B;
    u16* A1p = (u16*)w;                  w += AW_B;
    u16* A2p = (u16*)w;                  w += AW_B;
    u16* A3p = (u16*)w;                  w += AW_B;
    float* PnT = (float*)w;              w += 12800 * 4;
    float* pn2 = (float*)w;              w += 128 * 4;
    float* feats = (float*)w;            w += 8192 * 4;    // [2 ab][32][128]
    float* meanbuf = (float*)w;          w += 16384 * 4;   // [2 kind][2 ab][32][128]
    float* pr = (float*)w;               w += 16 * 4;
    float* mo = (float*)w;               w += 384 * 4;
    float* out = (float*)d_out;

    hipMemsetAsync(feats, 0, (8192 + 16384 + 16) * sizeof(float), stream);

    k_prep_w<<<1152, 256, 0, stream>>>(We, Wf, Wd, A1p, A2p, A3p);
    k_prox<<<NB, 128, 0, stream>>>(P, PnT, pn2);
    k_ring<<<dim3(32, 2), 256, 0, stream>>>(xpad, cpad);
    k_xpose<<<dim3(32, 16, 2), 256, 0, stream>>>(xa, xb, xpad, meanbuf);
    k_conv1g<<<dim3(4, 32, 4), 256, 0, stream>>>(xpad, A1p, cpad);
    k_cde9<<<dim3(2, 32, 6), 256, 0, stream>>>(cpad, A2p, A3p, xpad, feats, pr);
    k_metric<<<128, 128, 0, stream>>>(feats, meanbuf, PnT, pn2, la, lb, mo);
    k_final<<<1, 128, 0, stream>>>(pr, mo, out);
}

// Round 15
// 106.196 us; speedup vs baseline: 1.1324x; 1.0112x over previous
//
#include <hip/hip_runtime.h>
#include <hip/hip_bf16.h>

#define DEVI __device__ __forceinline__

constexpr int B_ = 32, CI = 128, CM = 256, H_ = 32, W_ = 32;
constexpr int S_ = 1024, NB = 100;
constexpr float LAMF = 0.7f, ILAMF = 0.3f, SCALEF = 3.0f;
// chunked channel-last activation layouts: [b][ch/8][pos][8ch]
constexpr size_t XSZ = (size_t)32 * 16 * 1156 * 8;   // per-ab xpad elems (34x34 pos)
constexpr size_t XBS = (size_t)16 * 1156 * 8;        // per-b stride
constexpr size_t CSZ = (size_t)32 * 32 * 324 * 8;    // per-ab cpad elems (18x18 pos)
constexpr size_t CBS = (size_t)32 * 324 * 8;

typedef short bf8 __attribute__((ext_vector_type(8)));
typedef float f4 __attribute__((ext_vector_type(4)));
typedef float f16v __attribute__((ext_vector_type(16)));
typedef unsigned short u16;
typedef unsigned int u32;

struct alignas(8) us4 { u16 v[4]; };
struct alignas(16) us8 { u16 v[8]; };

// deconv tap order, parity-grouped: par0{0,2,6,8} par3{4} | par1{1,7} par2{3,5}
__device__ __constant__ int TAPD9c[9] = {0, 2, 6, 8, 1, 7, 3, 5, 4};

DEVI u16 f2bf(float f) {
    unsigned u = __builtin_bit_cast(unsigned, f);
    u += 0x7FFFu + ((u >> 16) & 1u);
    return (u16)(u >> 16);
}
DEVI float bf2f(u16 h) {
    unsigned u = ((unsigned)h) << 16;
    return __builtin_bit_cast(float, u);
}

DEVI void gll16(const void* g, void* l) {
    __builtin_amdgcn_global_load_lds(
        (const __attribute__((address_space(1))) u32*)g,
        (__attribute__((address_space(3))) u32*)l, 16, 0, 0);
}

DEVI float waveSum(float v) {
#pragma unroll
    for (int off = 32; off > 0; off >>= 1) v += __shfl_down(v, off, 64);
    return v;
}
DEVI float blockSum256(float v, float* lds4) {
    v = waveSum(v);
    int wid = threadIdx.x >> 6, lane = threadIdx.x & 63;
    __syncthreads();
    if (lane == 0) lds4[wid] = v;
    __syncthreads();
    return lds4[0] + lds4[1] + lds4[2] + lds4[3];
}
DEVI float blockSum128(float v, float* lds2) {
    v = waveSum(v);
    int wid = threadIdx.x >> 6, lane = threadIdx.x & 63;
    __syncthreads();
    if (lane == 0) lds2[wid] = v;
    __syncthreads();
    return lds2[0] + lds2[1];
}
DEVI float blockMax128(float v, float* lds2) {
#pragma unroll
    for (int off = 32; off > 0; off >>= 1) v = fmaxf(v, __shfl_down(v, off, 64));
    int wid = threadIdx.x >> 6, lane = threadIdx.x & 63;
    __syncthreads();
    if (lane == 0) lds2[wid] = v;
    __syncthreads();
    return fmaxf(lds2[0], lds2[1]);
}

// ---- weight prep: staging-linear k-slot-major layouts (unchanged from R8) ----
__global__ __launch_bounds__(256) void k_prep_w(const float* __restrict__ We,
                                                const float* __restrict__ Wf,
                                                const float* __restrict__ Wd,
                                                u16* __restrict__ A1p,
                                                u16* __restrict__ A2p,
                                                u16* __restrict__ A3p) {
    int i = blockIdx.x * 256 + threadIdx.x;  // 294912
    {
        int e = i & 7, s = (i >> 3) & 511, j = i >> 12;  // j 0..71
        int Mt = j / 36, kc = j - Mt * 36;
        int tap = kc >> 2, cq = kc & 3;
        int q = s >> 7, m = s & 127;
        int oc = Mt * 128 + m, ch = cq * 32 + q * 8 + e;
        A1p[i] = f2bf(We[((size_t)oc * CI + ch) * 9 + tap]);
    }
    {
        int e = i & 7, s = (i >> 3) & 511, kc = i >> 12;  // 0..71
        int tapi = kc >> 3, cq = kc & 7;
        int q = s >> 7, m = s & 127;
        int ch = cq * 32 + q * 8 + e;
        A2p[i] = f2bf(Wf[((size_t)m * CM + ch) * 9 + tapi]);
        A3p[i] = f2bf(Wd[((size_t)m * CM + ch) * 9 + TAPD9c[tapi]]);
    }
}

// ---- proxies ----
__global__ __launch_bounds__(128) void k_prox(const float* __restrict__ P,
                                              float* __restrict__ PnT,
                                              float* __restrict__ pn2) {
    __shared__ float lds2[2];
    int k = blockIdx.x, t = threadIdx.x;
    float v = P[k * CI + t];
    float ss = blockSum128(v * v, lds2);
    float sc = SCALEF / fmaxf(sqrtf(ss), 1e-12f);
    float pv = v * sc;
    PnT[t * NB + k] = pv;
    float s2 = blockSum128(pv * pv, lds2);
    if (t == 0) pn2[k] = s2;
}

// ---- zero the padding rings of xpad and cpad ----
__global__ __launch_bounds__(256) void k_ring(u16* __restrict__ xpad, u16* __restrict__ cpad) {
    int b = blockIdx.x, ab = blockIdx.y, t = threadIdx.x;
    u16* xp = xpad + (size_t)ab * XSZ + (size_t)b * XBS;
    u16* cp = cpad + (size_t)ab * CSZ + (size_t)b * CBS;
    us8 z = {};
    for (int i = t; i < 132 * 16; i += 256) {
        int cc = i / 132, rp = i - cc * 132;
        int pos;
        if (rp < 68) pos = (rp < 34) ? (32 * 34 + rp) : (33 * 34 + rp - 34);
        else { int r2 = rp - 68; pos = (r2 >> 1) * 34 + 32 + (r2 & 1); }
        *(us8*)(xp + ((size_t)cc * 1156 + pos) * 8) = z;
    }
    for (int i = t; i < 68 * 32; i += 256) {
        int cc = i / 68, rp = i - cc * 68;
        int pos;
        if (rp < 36) pos = (rp < 18) ? rp : (17 * 18 + rp - 18);
        else { int r2 = rp - 36; pos = (1 + (r2 >> 1)) * 18 + ((r2 & 1) ? 17 : 0); }
        *(us8*)(cp + ((size_t)cc * 324 + pos) * 8) = z;
    }
}

// ---- fused: x -> bf16 chunked xpad + invd (LDS-only) + meanx/meanfl ----
__global__ __launch_bounds__(256) void k_xpose(const float* __restrict__ xa,
                                               const float* __restrict__ xb,
                                               u16* __restrict__ xpad,
                                               float* __restrict__ meanbuf) {
    __shared__ float ldsx[128][64];   // 32KB
    __shared__ float sred[256];
    __shared__ float sinv[64];
    int b = blockIdx.x, yg = blockIdx.y, ab = blockIdx.z;
    int t = threadIdx.x;
    const float* x = (ab ? xb : xa) + (size_t)b * CI * S_ + yg * 64;
    int c4 = t >> 6, p = t & 63;
    for (int c0 = 0; c0 < 32; ++c0) {
        int c = c0 * 4 + c4;
        ldsx[c][p] = x[(size_t)c * S_ + p];
    }
    __syncthreads();
    int qc = t >> 6;
    int y = yg * 2 + (p >> 5), xcol = p & 31;
    u16* ox = xpad + (size_t)ab * XSZ + (size_t)b * XBS;
    float ss = 0.f;
#pragma unroll
    for (int c8 = 0; c8 < 4; ++c8) {
        int cb = qc * 32 + c8 * 8;
        int cc = cb >> 3;
        us8 pk;
#pragma unroll
        for (int j = 0; j < 8; ++j) {
            float v = ldsx[cb + j][p];
            ss = fmaf(v, v, ss);
            pk.v[j] = f2bf(v);
        }
        *(us8*)(ox + ((size_t)cc * 1156 + y * 34 + xcol) * 8) = pk;
    }
    sred[t] = ss;
    __syncthreads();
    if (t < 64) {
        float s = sred[t] + sred[t + 64] + sred[t + 128] + sred[t + 192];
        sinv[t] = 1.f / fmaxf(sqrtf(s), 1e-12f);
    }
    __syncthreads();
    int c = t >> 1, h = t & 1;
    float sx = 0.f, sf = 0.f;
    for (int i = 0; i < 32; ++i) {
        int p2 = h * 32 + ((i + c) & 31);
        float v = ldsx[c][p2];
        sx += v;
        sf = fmaf(v, sinv[p2], sf);
    }
    sx += __shfl_xor(sx, 1, 64);
    sf += __shfl_xor(sf, 1, 64);
    if (!(t & 1)) {
        atomicAdd(&meanbuf[(size_t)ab * 4096 + b * 128 + c], sx * (1.f / 1024.f));
        atomicAdd(&meanbuf[8192 + (size_t)ab * 4096 + b * 128 + c], sf * (1.f / 1024.f));
    }
}

// ---- conv1: K-64 steps (18), tile M128 x N64, LDS dbuf (unchanged from R8) ----
__global__ __launch_bounds__(256, 2) void k_conv1g(const u16* __restrict__ XC,
                                                   const u16* __restrict__ A1p,
                                                   u16* __restrict__ CC) {
    __shared__ u16 sA[2][8192];
    __shared__ u16 sB[2][4096];
    int t = threadIdx.x, l = t & 63, l15 = l & 15, lq = l >> 4, w = t >> 6;
    int wm = w & 1, wn = w >> 1;
    int Nt = blockIdx.x, b = blockIdx.y;
    int ab = blockIdx.z & 1, Mt = blockIdx.z >> 1;
    const u16* xc = XC + (size_t)ab * XSZ + (size_t)b * XBS;
    const u16* Ag = A1p + (size_t)Mt * (36 * 4096);
    int bpos0 = (8 * Nt + 2 * (l >> 4)) * 34 + 2 * (l & 15);
    const int po1[9] = {0, 1, 2, 34, 35, 36, 68, 69, 70};

    auto stageA = [&](int buf, int kcA) {
        const u16* ga = Ag + (size_t)kcA * 4096 + t * 8;
        u16* da = &sA[buf][w * 512];
#pragma unroll
        for (int i = 0; i < 4; ++i) gll16(ga + i * 2048, da + i * 2048);
    };
    auto stageB = [&](int buf, int po, int s) {
#pragma unroll
        for (int i = 0; i < 2; ++i) {
            int ks = i * 4 + w;
            gll16(xc + ((size_t)(s * 8 + ks) * 1156 + bpos0 + po) * 8,
                  &sB[buf][(size_t)ks * 512]);
        }
    };

    f4 acc[4][2] = {};
    stageA(0, 0);
    stageB(0, 0, 0);
    int cur = 0;
#pragma unroll
    for (int ti = 0; ti < 9; ++ti) {
        const int po = po1[ti];
        const int poN = (ti < 8) ? po1[ti + 1] : 0;
#pragma unroll 1
        for (int s = 0; s < 2; ++s) {
            __syncthreads();
            bool last = (ti == 8) && (s == 1);
            if (!last) {
                int tin = (s < 1) ? ti : ti + 1;
                int sn = (s < 1) ? 1 : 0;
                stageA(cur ^ 1, tin * 4 + sn * 2);
                stageB(cur ^ 1, (s < 1) ? po : poN, sn);
            }
            const u16* As = sA[cur];
            const u16* Bs = sB[cur];
#pragma unroll
            for (int kc2 = 0; kc2 < 2; ++kc2) {
                bf8 af[4], bv[2];
#pragma unroll
                for (int mf = 0; mf < 4; ++mf)
                    af[mf] = *(const bf8*)(As + ((kc2 * 4 + lq) * 128 + wm * 64 + mf * 16 + l15) * 8);
#pragma unroll
                for (int nf = 0; nf < 2; ++nf)
                    bv[nf] = *(const bf8*)(Bs + ((kc2 * 4 + lq) * 64 + wn * 32 + nf * 16 + l15) * 8);
#pragma unroll
                for (int mf = 0; mf < 4; ++mf)
#pragma unroll
                    for (int nf = 0; nf < 2; ++nf)
                        acc[mf][nf] = __builtin_amdgcn_mfma_f32_16x16x32_bf16(af[mf], bv[nf], acc[mf][nf], 0, 0, 0);
            }
            cur ^= 1;
        }
    }
    u16* cb = CC + (size_t)ab * CSZ + (size_t)b * CBS;
#pragma unroll
    for (int mf = 0; mf < 4; ++mf) {
        int mc = Mt * 128 + wm * 64 + mf * 16 + lq * 4;
#pragma unroll
        for (int nf = 0; nf < 2; ++nf) {
            int nl = wn * 32 + nf * 16 + l15;
            int oh = Nt * 4 + (nl >> 4), ow = nl & 15;
            int posO = (1 + oh) * 18 + 1 + ow;
            us4 pk;
#pragma unroll
            for (int r = 0; r < 4; ++r) pk.v[r] = f2bf(fmaxf(acc[mf][nf][r], 0.f));
            *(us4*)(cb + ((size_t)(mc >> 3) * 324 + posO) * 8 + (mc & 7)) = pk;
        }
    }
}

// ---- k_cde10: (h,sub)-outer loop -> 22.5KB slab -> 2 blocks/CU ----
// Slab holds ONE 64-ch (h,sub) slice (8 chunks); restaged 4x. A streams as before.
// Per K-64 step: 16 ds_read_b128 + 16 mfma_32x32x16. Sync skeleton = R11 template.
// grid (2 Nt, 32 b, 6: type*2+ab)

#define KSTEP(ACC, KYV, KXV, HN, KCAN)                                              \
    {                                                                               \
        __syncthreads();                                                            \
        if (HN) stageA(cur ^ 1, (KCAN));                                            \
        const u16* As = sA[cur];                                                    \
        _Pragma("unroll") for (int kc2 = 0; kc2 < 2; ++kc2) {                       \
            _Pragma("unroll") for (int j = 0; j < 2; ++j) {                         \
                bf8 a0 = *(const bf8*)(As + kc2 * 4096 + j * 2048 + aBase);         \
                bf8 a1 = *(const bf8*)(As + kc2 * 4096 + j * 2048 + aBase + 256);   \
                const u16* bp = sS + (kc2 * 720 + j * 360) * 8 + bBase;             \
                bf8 b0 = *(const bf8*)(bp + (((KYV)) * 18 + (KXV)) * 8);            \
                bf8 b1 = *(const bf8*)(bp + (((KYV) + 2) * 18 + (KXV)) * 8);        \
                ACC[0][0] = __builtin_amdgcn_mfma_f32_32x32x16_bf16(a0, b0, ACC[0][0], 0, 0, 0); \
                ACC[0][1] = __builtin_amdgcn_mfma_f32_32x32x16_bf16(a0, b1, ACC[0][1], 0, 0, 0); \
                ACC[1][0] = __builtin_amdgcn_mfma_f32_32x32x16_bf16(a1, b0, ACC[1][0], 0, 0, 0); \
                ACC[1][1] = __builtin_amdgcn_mfma_f32_32x32x16_bf16(a1, b1, ACC[1][1], 0, 0, 0); \
            }                                                                       \
        }                                                                           \
        cur ^= 1;                                                                   \
    }

#define FLUSH(ACC, PY, PX)                                                          \
    _Pragma("unroll") for (int mf = 0; mf < 2; ++mf) {                              \
        _Pragma("unroll") for (int nf = 0; nf < 2; ++nf) {                          \
            int n = wn * 64 + nf * 32 + l31;                                        \
            int oh = 8 * Nt + (n >> 4), ow = n & 15;                                \
            int Y = 2 * oh + (PY), X = 2 * ow + (PX);                               \
            _Pragma("unroll") for (int rg = 0; rg < 4; ++rg) {                      \
                int mc = wm * 64 + mf * 32 + 8 * rg + 4 * lh;                       \
                us4 xv = *(const us4*)(xq + (size_t)(mc >> 3) * 1156 * 8 +          \
                                       (size_t)(Y * 34 + X) * 8 + (mc & 7));        \
                _Pragma("unroll") for (int r = 0; r < 4; ++r) {                     \
                    float d = ACC[mf][nf][rg * 4 + r] - bf2f(xv.v[r]);              \
                    ss = fmaf(d, d, ss);                                            \
                }                                                                   \
            }                                                                       \
        }                                                                           \
    }

__global__ __launch_bounds__(256, 2) void k_cde10(const u16* __restrict__ CC,
                                                  const u16* __restrict__ A2p,
                                                  const u16* __restrict__ A3p,
                                                  const u16* __restrict__ XC,
                                                  float* __restrict__ feats,
                                                  float* __restrict__ pr) {
    __shared__ u16 sS[11520];     // [ccL8][pos 10x18][8e] = 22.5KB (one (h,sub) slice)
    __shared__ u16 sA[2][8192];   // A dbuf 2x16KB
    __shared__ float lds4[4];
    int t = threadIdx.x, l = t & 63, l31 = l & 31, lh = l >> 5, w = t >> 6;
    int wm = w & 1, wn = w >> 1;
    int Nt = blockIdx.x, b = blockIdx.y;
    int ab = blockIdx.z & 1, type = blockIdx.z >> 1;
    const u16* cbb = CC + (size_t)ab * CSZ + (size_t)b * CBS;
    const u16* xq = XC + (size_t)ab * XSZ + (size_t)b * XBS;
    const u16* Ag = type ? A3p : A2p;
    int r0 = 8 * Nt;
    int aBase = (lh * 128 + wm * 64 + l31) * 8;
    int bBase = (lh * 180 + (wn * 4 + (l31 >> 4)) * 18 + (l31 & 15)) * 8;

    auto stageA = [&](int buf, int kcA) {   // 2 chunks = 16KB contiguous
        const u16* ga = Ag + (size_t)kcA * 4096 + t * 8;
        u16* da = &sA[buf][w * 512];
#pragma unroll
        for (int i = 0; i < 4; ++i) gll16(ga + i * 2048, da + i * 2048);
    };
    auto stage_slab = [&](int seg) {        // 8 chunks of the (h,sub) slice
        if (t < 180) {
            int cc0 = (seg >> 1) * 16 + (seg & 1) * 8;
#pragma unroll 1
            for (int ccL = 0; ccL < 8; ++ccL) {
                us8 v = *(const us8*)(cbb + ((size_t)(cc0 + ccL) * 324 + r0 * 18 + t) * 8);
                *(us8*)(sS + ((size_t)ccL * 180 + t) * 8) = v;
            }
        }
    };

    int cur = 0;
    float ss = 0.f;
    if (type == 0) {
        // conv2: 36 steps = seg(4: h,sub) x tap(9). kcA = tap*8 + h*4 + sub*2.
        f16v acc[2][2] = {};
        stage_slab(0);
        stageA(0, 0);
#pragma unroll
        for (int seg = 0; seg < 4; ++seg) {
            if (seg) { __syncthreads(); stage_slab(seg); }
#pragma unroll 1
            for (int tap = 0; tap < 9; ++tap) {
                int s = seg * 9 + tap;
                int ky = tap / 3, kx = tap - ky * 3;
                bool hn = s < 35;
                int s1 = hn ? s + 1 : 0;
                int seg1 = s1 / 9, tap1 = s1 - seg1 * 9;
                int kcan = tap1 * 8 + (seg1 >> 1) * 4 + (seg1 & 1) * 2;
                KSTEP(acc, ky, kx, hn, kcan);
            }
        }
        float* fo = feats + ((size_t)ab * B_ + b) * CI;
#pragma unroll
        for (int mf = 0; mf < 2; ++mf)
#pragma unroll
            for (int reg = 0; reg < 16; ++reg) {
                float v = fmaxf(acc[mf][0][reg], 0.f) + fmaxf(acc[mf][1][reg], 0.f);
                v += __shfl_xor(v, 1, 64);
                v += __shfl_xor(v, 2, 64);
                v += __shfl_xor(v, 4, 64);
                v += __shfl_xor(v, 8, 64);
                v += __shfl_xor(v, 16, 64);
                if (l31 == 0)
                    atomicAdd(fo + wm * 64 + mf * 32 + (reg & 3) + 8 * (reg >> 2) + 4 * lh,
                              v * (1.f / 256.f));
            }
    } else if (type == 1) {
        // 20 steps = seg(4) x r(5): r<4 -> accP taps{0,2,6,8} (tapi=r), r=4 -> accQ tap4 (tapi=8)
        f16v accP[2][2] = {}, accQ[2][2] = {};
        stage_slab(0);
        stageA(0, 0);
#pragma unroll
        for (int seg = 0; seg < 4; ++seg) {
            if (seg) { __syncthreads(); stage_slab(seg); }
#pragma unroll 1
            for (int r = 0; r < 5; ++r) {
                int s = seg * 5 + r;
                bool hn = s < 19;
                int s1 = hn ? s + 1 : 0;
                int seg1 = s1 / 5, r1 = s1 - seg1 * 5;
                int tapi1 = (r1 < 4) ? r1 : 8;
                int kcan = tapi1 * 8 + (seg1 >> 1) * 4 + (seg1 & 1) * 2;
                if (r < 4) {
                    int dy = r >> 1, dx = r & 1;
                    KSTEP(accP, dy, dx, hn, kcan);
                } else {
                    KSTEP(accQ, 1, 1, hn, kcan);
                }
            }
        }
        FLUSH(accP, 0, 0);
        FLUSH(accQ, 1, 1);
        ss = blockSum256(ss, lds4);
        if (t == 0) atomicAdd(pr + ab, ss);
    } else {
        // 16 steps = seg(4) x r(4): r<2 -> accP taps{1,7} (tapi=4+r), r>=2 -> accQ taps{3,5} (tapi=4+r)
        f16v accP[2][2] = {}, accQ[2][2] = {};
        stage_slab(0);
        stageA(0, 32);
#pragma unroll
        for (int seg = 0; seg < 4; ++seg) {
            if (seg) { __syncthreads(); stage_slab(seg); }
#pragma unroll 1
            for (int r = 0; r < 4; ++r) {
                int s = seg * 4 + r;
                bool hn = s < 15;
                int s1 = hn ? s + 1 : 0;
                int seg1 = s1 >> 2, r1 = s1 & 3;
                int kcan = (4 + r1) * 8 + (seg1 >> 1) * 4 + (seg1 & 1) * 2;
                if (r < 2) {
                    KSTEP(accP, r, 1, hn, kcan);
                } else {
                    KSTEP(accQ, 1, r - 2, hn, kcan);
                }
            }
        }
        FLUSH(accP, 0, 1);
        FLUSH(accQ, 1, 0);
        ss = blockSum256(ss, lds4);
        if (t == 0) atomicAdd(pr + ab, ss);
    }
}

#undef KSTEP
#undef FLUSH

// ---- metric (mix fused: sets 2/3 from meanbuf; Sinkhorn dead code) ----
__global__ __launch_bounds__(128) void k_metric(const float* __restrict__ feats,
                                                const float* __restrict__ meanbuf,
                                                const float* __restrict__ PnT,
                                                const float* __restrict__ pn2,
                                                const int* __restrict__ la,
                                                const int* __restrict__ lb,
                                                float* __restrict__ mo) {
    __shared__ float lds2[2];
    __shared__ float xs[128];
    int blk = blockIdx.x;
    int t = threadIdx.x;
    int b = blk & 31;
    float xv;
    if (blk < 64) xv = feats[(size_t)blk * CI + t];
    else if (blk < 96) xv = LAMF * meanbuf[b * 128 + t] + ILAMF * meanbuf[12288 + b * 128 + t];
    else xv = LAMF * meanbuf[4096 + b * 128 + t] + ILAMF * meanbuf[8192 + b * 128 + t];
    float ssq = blockSum128(xv * xv, lds2);
    float sc = SCALEF / fmaxf(sqrtf(ssq), 1e-12f);
    float xn = xv * sc;
    xs[t] = xn;
    float xn2 = blockSum128(xn * xn, lds2);
    bool active = (t < NB);
    float Dk = 1e30f;
    if (active) {
        float dot = 0.f;
#pragma unroll 8
        for (int e = 0; e < CI; ++e) dot = fmaf(xs[e], PnT[e * NB + t], dot);
        Dk = xn2 + pn2[t] - 2.f * dot;
    }
    float z = active ? -Dk : -1e30f;
    float m = blockMax128(z, lds2);
    float e = active ? expf(z - m) : 0.f;
    float se = blockSum128(e, lds2);
    float lse = m + logf(se);
    if (t == 0) mo[blk * 3 + 0] = lse;
    int A = la[b], Bb = lb[b];
    if (t == A) mo[blk * 3 + 1] = Dk;
    if (t == Bb) mo[blk * 3 + 2] = Dk;
}

__global__ __launch_bounds__(128) void k_final(const float* __restrict__ pr,
                                               const float* __restrict__ mo,
                                               float* __restrict__ out) {
    __shared__ float mla[4], mlb[4];
    int t = threadIdx.x;
    const float* m = mo + t * 3;
    float ula = m[0] + m[1];
    float ulb = m[0] + m[2];
#pragma unroll
    for (int off = 16; off > 0; off >>= 1) {
        ula += __shfl_down(ula, off, 32);
        ulb += __shfl_down(ulb, off, 32);
    }
    if ((t & 31) == 0) { mla[t >> 5] = ula * (1.f / 32.f); mlb[t >> 5] = ulb * (1.f / 32.f); }
    __syncthreads();
    if (t == 0) {
        float lxa = pr[0] * (1.f / 4194304.f);
        float lxb = pr[1] * (1.f / 4194304.f);
        float lca = mla[0];
        float lcb = mlb[1];
        float lcma = LAMF * mla[2] + ILAMF * mlb[2];
        float lcmb = LAMF * mlb[3] + ILAMF * mla[3];
        out[0] = lxa + lxb + lca + lcb + lcma + lcmb;
        out[1] = lxa; out[2] = lxb; out[3] = lca; out[4] = lcb; out[5] = lcma; out[6] = lcmb;
    }
}

extern "C" void kernel_launch(void* const* d_in, const int* in_sizes, int n_in,
                              void* d_out, int out_size, void* d_ws, size_t ws_size,
                              hipStream_t stream) {
    const float* xa = (const float*)d_in[0];
    const float* xb = (const float*)d_in[1];
    const int* la = (const int*)d_in[2];
    const int* lb = (const int*)d_in[3];
    const float* P = (const float*)d_in[4];
    const float* We = (const float*)d_in[5];
    const float* Wf = (const float*)d_in[6];
    const float* Wd = (const float*)d_in[7];

    char* w = (char*)d_ws;
    const size_t XPAD_B = XSZ * 2 * sizeof(u16);
    const size_t CPAD_B = CSZ * 2 * sizeof(u16);
    const size_t AW_B = (size_t)294912 * 2;
    u16* xpad = (u16*)w;                 w += XPAD_B;
    u16* cpad = (u16*)w;                 w += CPAD_B;
    u16* A1p = (u16*)w;                  w += AW_B;
    u16* A2p = (u16*)w;                  w += AW_B;
    u16* A3p = (u16*)w;                  w += AW_B;
    float* PnT = (float*)w;              w += 12800 * 4;
    float* pn2 = (float*)w;              w += 128 * 4;
    float* feats = (float*)w;            w += 8192 * 4;    // [2 ab][32][128]
    float* meanbuf = (float*)w;          w += 16384 * 4;   // [2 kind][2 ab][32][128]
    float* pr = (float*)w;               w += 16 * 4;
    float* mo = (float*)w;               w += 384 * 4;
    float* out = (float*)d_out;

    hipMemsetAsync(feats, 0, (8192 + 16384 + 16) * sizeof(float), stream);

    k_prep_w<<<1152, 256, 0, stream>>>(We, Wf, Wd, A1p, A2p, A3p);
    k_prox<<<NB, 128, 0, stream>>>(P, PnT, pn2);
    k_ring<<<dim3(32, 2), 256, 0, stream>>>(xpad, cpad);
    k_xpose<<<dim3(32, 16, 2), 256, 0, stream>>>(xa, xb, xpad, meanbuf);
    k_conv1g<<<dim3(4, 32, 4), 256, 0, stream>>>(xpad, A1p, cpad);
    k_cde10<<<dim3(2, 32, 6), 256, 0, stream>>>(cpad, A2p, A3p, xpad, feats, pr);
    k_metric<<<128, 128, 0, stream>>>(feats, meanbuf, PnT, pn2, la, lb, mo);
    k_final<<<1, 128, 0, stream>>>(pr, mo, out);
}

// Round 16
// 103.625 us; speedup vs baseline: 1.1605x; 1.0248x over previous
//
#include <hip/hip_runtime.h>
#include <hip/hip_bf16.h>

#define DEVI __device__ __forceinline__

constexpr int B_ = 32, CI = 128, CM = 256, H_ = 32, W_ = 32;
constexpr int S_ = 1024, NB = 100;
constexpr float LAMF = 0.7f, ILAMF = 0.3f, SCALEF = 3.0f;
// chunked channel-last activation layouts: [b][ch/8][pos][8ch]
constexpr size_t XSZ = (size_t)32 * 16 * 1156 * 8;   // per-ab xpad elems (34x34 pos)
constexpr size_t XBS = (size_t)16 * 1156 * 8;        // per-b stride
constexpr size_t CSZ = (size_t)32 * 32 * 324 * 8;    // per-ab cpad elems (18x18 pos)
constexpr size_t CBS = (size_t)32 * 324 * 8;

typedef short bf8 __attribute__((ext_vector_type(8)));
typedef float f4 __attribute__((ext_vector_type(4)));
typedef float f16v __attribute__((ext_vector_type(16)));
typedef unsigned short u16;
typedef unsigned int u32;

struct alignas(8) us4 { u16 v[4]; };
struct alignas(16) us8 { u16 v[8]; };

// deconv tap order, parity-grouped: par0{0,2,6,8} par3{4} | par1{1,7} par2{3,5}
__device__ __constant__ int TAPD9c[9] = {0, 2, 6, 8, 1, 7, 3, 5, 4};

DEVI u16 f2bf(float f) {
    unsigned u = __builtin_bit_cast(unsigned, f);
    u += 0x7FFFu + ((u >> 16) & 1u);
    return (u16)(u >> 16);
}
DEVI float bf2f(u16 h) {
    unsigned u = ((unsigned)h) << 16;
    return __builtin_bit_cast(float, u);
}

DEVI void gll16(const void* g, void* l) {
    __builtin_amdgcn_global_load_lds(
        (const __attribute__((address_space(1))) u32*)g,
        (__attribute__((address_space(3))) u32*)l, 16, 0, 0);
}

DEVI float waveSum(float v) {
#pragma unroll
    for (int off = 32; off > 0; off >>= 1) v += __shfl_down(v, off, 64);
    return v;
}
DEVI float blockSum256(float v, float* lds4) {
    v = waveSum(v);
    int wid = threadIdx.x >> 6, lane = threadIdx.x & 63;
    __syncthreads();
    if (lane == 0) lds4[wid] = v;
    __syncthreads();
    return lds4[0] + lds4[1] + lds4[2] + lds4[3];
}
DEVI float blockSum128(float v, float* lds2) {
    v = waveSum(v);
    int wid = threadIdx.x >> 6, lane = threadIdx.x & 63;
    __syncthreads();
    if (lane == 0) lds2[wid] = v;
    __syncthreads();
    return lds2[0] + lds2[1];
}
DEVI float blockMax128(float v, float* lds2) {
#pragma unroll
    for (int off = 32; off > 0; off >>= 1) v = fmaxf(v, __shfl_down(v, off, 64));
    int wid = threadIdx.x >> 6, lane = threadIdx.x & 63;
    __syncthreads();
    if (lane == 0) lds2[wid] = v;
    __syncthreads();
    return fmaxf(lds2[0], lds2[1]);
}

// ---- weight prep: staging-linear k-slot-major layouts (unchanged from R8) ----
__global__ __launch_bounds__(256) void k_prep_w(const float* __restrict__ We,
                                                const float* __restrict__ Wf,
                                                const float* __restrict__ Wd,
                                                u16* __restrict__ A1p,
                                                u16* __restrict__ A2p,
                                                u16* __restrict__ A3p) {
    int i = blockIdx.x * 256 + threadIdx.x;  // 294912
    {
        int e = i & 7, s = (i >> 3) & 511, j = i >> 12;  // j 0..71
        int Mt = j / 36, kc = j - Mt * 36;
        int tap = kc >> 2, cq = kc & 3;
        int q = s >> 7, m = s & 127;
        int oc = Mt * 128 + m, ch = cq * 32 + q * 8 + e;
        A1p[i] = f2bf(We[((size_t)oc * CI + ch) * 9 + tap]);
    }
    {
        int e = i & 7, s = (i >> 3) & 511, kc = i >> 12;  // 0..71
        int tapi = kc >> 3, cq = kc & 7;
        int q = s >> 7, m = s & 127;
        int ch = cq * 32 + q * 8 + e;
        A2p[i] = f2bf(Wf[((size_t)m * CM + ch) * 9 + tapi]);
        A3p[i] = f2bf(Wd[((size_t)m * CM + ch) * 9 + TAPD9c[tapi]]);
    }
}

// ---- proxies ----
__global__ __launch_bounds__(128) void k_prox(const float* __restrict__ P,
                                              float* __restrict__ PnT,
                                              float* __restrict__ pn2) {
    __shared__ float lds2[2];
    int k = blockIdx.x, t = threadIdx.x;
    float v = P[k * CI + t];
    float ss = blockSum128(v * v, lds2);
    float sc = SCALEF / fmaxf(sqrtf(ss), 1e-12f);
    float pv = v * sc;
    PnT[t * NB + k] = pv;
    float s2 = blockSum128(pv * pv, lds2);
    if (t == 0) pn2[k] = s2;
}

// ---- zero the padding rings of xpad and cpad ----
__global__ __launch_bounds__(256) void k_ring(u16* __restrict__ xpad, u16* __restrict__ cpad) {
    int b = blockIdx.x, ab = blockIdx.y, t = threadIdx.x;
    u16* xp = xpad + (size_t)ab * XSZ + (size_t)b * XBS;
    u16* cp = cpad + (size_t)ab * CSZ + (size_t)b * CBS;
    us8 z = {};
    for (int i = t; i < 132 * 16; i += 256) {
        int cc = i / 132, rp = i - cc * 132;
        int pos;
        if (rp < 68) pos = (rp < 34) ? (32 * 34 + rp) : (33 * 34 + rp - 34);
        else { int r2 = rp - 68; pos = (r2 >> 1) * 34 + 32 + (r2 & 1); }
        *(us8*)(xp + ((size_t)cc * 1156 + pos) * 8) = z;
    }
    for (int i = t; i < 68 * 32; i += 256) {
        int cc = i / 68, rp = i - cc * 68;
        int pos;
        if (rp < 36) pos = (rp < 18) ? rp : (17 * 18 + rp - 18);
        else { int r2 = rp - 36; pos = (1 + (r2 >> 1)) * 18 + ((r2 & 1) ? 17 : 0); }
        *(us8*)(cp + ((size_t)cc * 324 + pos) * 8) = z;
    }
}

// ---- fused: x -> bf16 chunked xpad + invd (LDS-only) + meanx/meanfl ----
__global__ __launch_bounds__(256) void k_xpose(const float* __restrict__ xa,
                                               const float* __restrict__ xb,
                                               u16* __restrict__ xpad,
                                               float* __restrict__ meanbuf) {
    __shared__ float ldsx[128][64];   // 32KB
    __shared__ float sred[256];
    __shared__ float sinv[64];
    int b = blockIdx.x, yg = blockIdx.y, ab = blockIdx.z;
    int t = threadIdx.x;
    const float* x = (ab ? xb : xa) + (size_t)b * CI * S_ + yg * 64;
    int c4 = t >> 6, p = t & 63;
    for (int c0 = 0; c0 < 32; ++c0) {
        int c = c0 * 4 + c4;
        ldsx[c][p] = x[(size_t)c * S_ + p];
    }
    __syncthreads();
    int qc = t >> 6;
    int y = yg * 2 + (p >> 5), xcol = p & 31;
    u16* ox = xpad + (size_t)ab * XSZ + (size_t)b * XBS;
    float ss = 0.f;
#pragma unroll
    for (int c8 = 0; c8 < 4; ++c8) {
        int cb = qc * 32 + c8 * 8;
        int cc = cb >> 3;
        us8 pk;
#pragma unroll
        for (int j = 0; j < 8; ++j) {
            float v = ldsx[cb + j][p];
            ss = fmaf(v, v, ss);
            pk.v[j] = f2bf(v);
        }
        *(us8*)(ox + ((size_t)cc * 1156 + y * 34 + xcol) * 8) = pk;
    }
    sred[t] = ss;
    __syncthreads();
    if (t < 64) {
        float s = sred[t] + sred[t + 64] + sred[t + 128] + sred[t + 192];
        sinv[t] = 1.f / fmaxf(sqrtf(s), 1e-12f);
    }
    __syncthreads();
    int c = t >> 1, h = t & 1;
    float sx = 0.f, sf = 0.f;
    for (int i = 0; i < 32; ++i) {
        int p2 = h * 32 + ((i + c) & 31);
        float v = ldsx[c][p2];
        sx += v;
        sf = fmaf(v, sinv[p2], sf);
    }
    sx += __shfl_xor(sx, 1, 64);
    sf += __shfl_xor(sf, 1, 64);
    if (!(t & 1)) {
        atomicAdd(&meanbuf[(size_t)ab * 4096 + b * 128 + c], sx * (1.f / 1024.f));
        atomicAdd(&meanbuf[8192 + (size_t)ab * 4096 + b * 128 + c], sf * (1.f / 1024.f));
    }
}

// ---- conv1: K-64 steps (18), tile M128 x N64, LDS dbuf (unchanged from R8) ----
__global__ __launch_bounds__(256, 2) void k_conv1g(const u16* __restrict__ XC,
                                                   const u16* __restrict__ A1p,
                                                   u16* __restrict__ CC) {
    __shared__ u16 sA[2][8192];
    __shared__ u16 sB[2][4096];
    int t = threadIdx.x, l = t & 63, l15 = l & 15, lq = l >> 4, w = t >> 6;
    int wm = w & 1, wn = w >> 1;
    int Nt = blockIdx.x, b = blockIdx.y;
    int ab = blockIdx.z & 1, Mt = blockIdx.z >> 1;
    const u16* xc = XC + (size_t)ab * XSZ + (size_t)b * XBS;
    const u16* Ag = A1p + (size_t)Mt * (36 * 4096);
    int bpos0 = (8 * Nt + 2 * (l >> 4)) * 34 + 2 * (l & 15);
    const int po1[9] = {0, 1, 2, 34, 35, 36, 68, 69, 70};

    auto stageA = [&](int buf, int kcA) {
        const u16* ga = Ag + (size_t)kcA * 4096 + t * 8;
        u16* da = &sA[buf][w * 512];
#pragma unroll
        for (int i = 0; i < 4; ++i) gll16(ga + i * 2048, da + i * 2048);
    };
    auto stageB = [&](int buf, int po, int s) {
#pragma unroll
        for (int i = 0; i < 2; ++i) {
            int ks = i * 4 + w;
            gll16(xc + ((size_t)(s * 8 + ks) * 1156 + bpos0 + po) * 8,
                  &sB[buf][(size_t)ks * 512]);
        }
    };

    f4 acc[4][2] = {};
    stageA(0, 0);
    stageB(0, 0, 0);
    int cur = 0;
#pragma unroll
    for (int ti = 0; ti < 9; ++ti) {
        const int po = po1[ti];
        const int poN = (ti < 8) ? po1[ti + 1] : 0;
#pragma unroll 1
        for (int s = 0; s < 2; ++s) {
            __syncthreads();
            bool last = (ti == 8) && (s == 1);
            if (!last) {
                int tin = (s < 1) ? ti : ti + 1;
                int sn = (s < 1) ? 1 : 0;
                stageA(cur ^ 1, tin * 4 + sn * 2);
                stageB(cur ^ 1, (s < 1) ? po : poN, sn);
            }
            const u16* As = sA[cur];
            const u16* Bs = sB[cur];
#pragma unroll
            for (int kc2 = 0; kc2 < 2; ++kc2) {
                bf8 af[4], bv[2];
#pragma unroll
                for (int mf = 0; mf < 4; ++mf)
                    af[mf] = *(const bf8*)(As + ((kc2 * 4 + lq) * 128 + wm * 64 + mf * 16 + l15) * 8);
#pragma unroll
                for (int nf = 0; nf < 2; ++nf)
                    bv[nf] = *(const bf8*)(Bs + ((kc2 * 4 + lq) * 64 + wn * 32 + nf * 16 + l15) * 8);
#pragma unroll
                for (int mf = 0; mf < 4; ++mf)
#pragma unroll
                    for (int nf = 0; nf < 2; ++nf)
                        acc[mf][nf] = __builtin_amdgcn_mfma_f32_16x16x32_bf16(af[mf], bv[nf], acc[mf][nf], 0, 0, 0);
            }
            cur ^= 1;
        }
    }
    u16* cb = CC + (size_t)ab * CSZ + (size_t)b * CBS;
#pragma unroll
    for (int mf = 0; mf < 4; ++mf) {
        int mc = Mt * 128 + wm * 64 + mf * 16 + lq * 4;
#pragma unroll
        for (int nf = 0; nf < 2; ++nf) {
            int nl = wn * 32 + nf * 16 + l15;
            int oh = Nt * 4 + (nl >> 4), ow = nl & 15;
            int posO = (1 + oh) * 18 + 1 + ow;
            us4 pk;
#pragma unroll
            for (int r = 0; r < 4; ++r) pk.v[r] = f2bf(fmaxf(acc[mf][nf][r], 0.f));
            *(us4*)(cb + ((size_t)(mc >> 3) * 324 + posO) * 8 + (mc & 7)) = pk;
        }
    }
}

// ---- k_cde11: 512 balanced blocks (~18 steps each), R14 skeleton ----
// units: u0 conv2 ch 0..127 -> pc0 (18 steps), u1 conv2 ch 128..255 -> pc1 (18),
// u2 deconv par{0,3} (20), u3 deconv par{1,2} (16). grid (2 Nt, 32 b, 8: unit*2+ab)

#define KSTEP(ACC, KYV, KXV, HN, KCAN)                                              \
    {                                                                               \
        __syncthreads();                                                            \
        if (HN) stageA(cur ^ 1, (KCAN));                                            \
        const u16* As = sA[cur];                                                    \
        _Pragma("unroll") for (int kc2 = 0; kc2 < 2; ++kc2) {                       \
            _Pragma("unroll") for (int j = 0; j < 2; ++j) {                         \
                bf8 a0 = *(const bf8*)(As + kc2 * 4096 + j * 2048 + aBase);         \
                bf8 a1 = *(const bf8*)(As + kc2 * 4096 + j * 2048 + aBase + 256);   \
                const u16* bp = sS + (kc2 * 720 + j * 360) * 8 + bBase;             \
                bf8 b0 = *(const bf8*)(bp + (((KYV)) * 18 + (KXV)) * 8);            \
                bf8 b1 = *(const bf8*)(bp + (((KYV) + 2) * 18 + (KXV)) * 8);        \
                ACC[0][0] = __builtin_amdgcn_mfma_f32_32x32x16_bf16(a0, b0, ACC[0][0], 0, 0, 0); \
                ACC[0][1] = __builtin_amdgcn_mfma_f32_32x32x16_bf16(a0, b1, ACC[0][1], 0, 0, 0); \
                ACC[1][0] = __builtin_amdgcn_mfma_f32_32x32x16_bf16(a1, b0, ACC[1][0], 0, 0, 0); \
                ACC[1][1] = __builtin_amdgcn_mfma_f32_32x32x16_bf16(a1, b1, ACC[1][1], 0, 0, 0); \
            }                                                                       \
        }                                                                           \
        cur ^= 1;                                                                   \
    }

#define FLUSH(ACC, PY, PX)                                                          \
    _Pragma("unroll") for (int mf = 0; mf < 2; ++mf) {                              \
        _Pragma("unroll") for (int nf = 0; nf < 2; ++nf) {                          \
            int n = wn * 64 + nf * 32 + l31;                                        \
            int oh = 8 * Nt + (n >> 4), ow = n & 15;                                \
            int Y = 2 * oh + (PY), X = 2 * ow + (PX);                               \
            _Pragma("unroll") for (int rg = 0; rg < 4; ++rg) {                      \
                int mc = wm * 64 + mf * 32 + 8 * rg + 4 * lh;                       \
                us4 xv = *(const us4*)(xq + (size_t)(mc >> 3) * 1156 * 8 +          \
                                       (size_t)(Y * 34 + X) * 8 + (mc & 7));        \
                _Pragma("unroll") for (int r = 0; r < 4; ++r) {                     \
                    float d = ACC[mf][nf][rg * 4 + r] - bf2f(xv.v[r]);              \
                    ss = fmaf(d, d, ss);                                            \
                }                                                                   \
            }                                                                       \
        }                                                                           \
    }

__global__ __launch_bounds__(256, 2) void k_cde11(const u16* __restrict__ CC,
                                                  const u16* __restrict__ A2p,
                                                  const u16* __restrict__ A3p,
                                                  const u16* __restrict__ XC,
                                                  float* __restrict__ pc0,
                                                  float* __restrict__ pc1,
                                                  float* __restrict__ pr) {
    __shared__ u16 sS[11520];     // [ccL8][pos 10x18][8e] = 22.5KB (one 32-ch seg)
    __shared__ u16 sA[2][8192];   // A dbuf 2x16KB
    __shared__ float lds4[4];
    int t = threadIdx.x, l = t & 63, l31 = l & 31, lh = l >> 5, w = t >> 6;
    int wm = w & 1, wn = w >> 1;
    int Nt = blockIdx.x, b = blockIdx.y;
    int ab = blockIdx.z & 1, unit = blockIdx.z >> 1;
    const u16* cbb = CC + (size_t)ab * CSZ + (size_t)b * CBS;
    const u16* xq = XC + (size_t)ab * XSZ + (size_t)b * XBS;
    const u16* Ag = (unit < 2) ? A2p : A3p;
    int r0 = 8 * Nt;
    int aBase = (lh * 128 + wm * 64 + l31) * 8;
    int bBase = (lh * 180 + (wn * 4 + (l31 >> 4)) * 18 + (l31 & 15)) * 8;

    auto stageA = [&](int buf, int kcA) {   // 2 chunks = 16KB contiguous
        const u16* ga = Ag + (size_t)kcA * 4096 + t * 8;
        u16* da = &sA[buf][w * 512];
#pragma unroll
        for (int i = 0; i < 4; ++i) gll16(ga + i * 2048, da + i * 2048);
    };
    auto stage_slab = [&](int seg) {        // 8 chunks of the 32-ch seg slice
        if (t < 180) {
            int cc0 = (seg >> 1) * 16 + (seg & 1) * 8;
#pragma unroll 1
            for (int ccL = 0; ccL < 8; ++ccL) {
                us8 v = *(const us8*)(cbb + ((size_t)(cc0 + ccL) * 324 + r0 * 18 + t) * 8);
                *(us8*)(sS + ((size_t)ccL * 180 + t) * 8) = v;
            }
        }
    };

    int cur = 0;
    float ss = 0.f;
    if (unit < 2) {
        // conv2 channel-half: segs {2*unit, 2*unit+1}, 18 steps -> raw partial
        f16v acc[2][2] = {};
        int segBase = unit * 2;
        stage_slab(segBase);
        stageA(0, (segBase >> 1) * 4 + (segBase & 1) * 2);
#pragma unroll
        for (int sl = 0; sl < 2; ++sl) {
            int seg = segBase + sl;
            if (sl) { __syncthreads(); stage_slab(seg); }
#pragma unroll 1
            for (int tap = 0; tap < 9; ++tap) {
                int s = sl * 9 + tap;
                int ky = tap / 3, kx = tap - ky * 3;
                bool hn = s < 17;
                int s1 = hn ? s + 1 : 0;
                int sl1 = s1 / 9, tap1 = s1 - sl1 * 9;
                int seg1 = segBase + sl1;
                int kcan = tap1 * 8 + (seg1 >> 1) * 4 + (seg1 & 1) * 2;
                KSTEP(acc, ky, kx, hn, kcan);
            }
        }
        float* pw = (unit == 0 ? pc0 : pc1) + (size_t)(ab * 32 + b) * 128 * 256;
#pragma unroll
        for (int mf = 0; mf < 2; ++mf)
#pragma unroll
            for (int nf = 0; nf < 2; ++nf)
#pragma unroll
                for (int reg = 0; reg < 16; ++reg) {
                    int oc = wm * 64 + mf * 32 + (reg & 3) + 8 * (reg >> 2) + 4 * lh;
                    int pos = 128 * Nt + wn * 64 + nf * 32 + l31;
                    pw[(size_t)oc * 256 + pos] = acc[mf][nf][reg];
                }
    } else if (unit == 2) {
        // deconv par{0,3}: 20 steps = seg(4) x r(5)
        f16v accP[2][2] = {}, accQ[2][2] = {};
        stage_slab(0);
        stageA(0, 0);
#pragma unroll
        for (int seg = 0; seg < 4; ++seg) {
            if (seg) { __syncthreads(); stage_slab(seg); }
#pragma unroll 1
            for (int r = 0; r < 5; ++r) {
                int s = seg * 5 + r;
                bool hn = s < 19;
                int s1 = hn ? s + 1 : 0;
                int seg1 = s1 / 5, r1 = s1 - seg1 * 5;
                int tapi1 = (r1 < 4) ? r1 : 8;
                int kcan = tapi1 * 8 + (seg1 >> 1) * 4 + (seg1 & 1) * 2;
                if (r < 4) {
                    int dy = r >> 1, dx = r & 1;
                    KSTEP(accP, dy, dx, hn, kcan);
                } else {
                    KSTEP(accQ, 1, 1, hn, kcan);
                }
            }
        }
        FLUSH(accP, 0, 0);
        FLUSH(accQ, 1, 1);
        ss = blockSum256(ss, lds4);
        if (t == 0) atomicAdd(pr + ab, ss);
    } else {
        // deconv par{1,2}: 16 steps = seg(4) x r(4)
        f16v accP[2][2] = {}, accQ[2][2] = {};
        stage_slab(0);
        stageA(0, 32);
#pragma unroll
        for (int seg = 0; seg < 4; ++seg) {
            if (seg) { __syncthreads(); stage_slab(seg); }
#pragma unroll 1
            for (int r = 0; r < 4; ++r) {
                int s = seg * 4 + r;
                bool hn = s < 15;
                int s1 = hn ? s + 1 : 0;
                int seg1 = s1 >> 2, r1 = s1 & 3;
                int kcan = (4 + r1) * 8 + (seg1 >> 1) * 4 + (seg1 & 1) * 2;
                if (r < 2) {
                    KSTEP(accP, r, 1, hn, kcan);
                } else {
                    KSTEP(accQ, 1, r - 2, hn, kcan);
                }
            }
        }
        FLUSH(accP, 0, 1);
        FLUSH(accQ, 1, 0);
        ss = blockSum256(ss, lds4);
        if (t == 0) atomicAdd(pr + ab, ss);
    }
}

#undef KSTEP
#undef FLUSH

// ---- conv2 epilogue: feats = mean(relu(pc0 + pc1)) ----
__global__ __launch_bounds__(256) void k_cfin(const float* __restrict__ pc0,
                                              const float* __restrict__ pc1,
                                              float* __restrict__ feats) {
    __shared__ float lds4[4];
    int ocg = blockIdx.x, b = blockIdx.y, ab = blockIdx.z;
    int t = threadIdx.x;
    const float* p0 = pc0 + (size_t)(ab * 32 + b) * 128 * 256;
    const float* p1 = pc1 + (size_t)(ab * 32 + b) * 128 * 256;
    float* fo = feats + (size_t)(ab * 32 + b) * 128;
#pragma unroll 1
    for (int i = 0; i < 16; ++i) {
        int oc = ocg * 16 + i;
        float v = fmaxf(p0[(size_t)oc * 256 + t] + p1[(size_t)oc * 256 + t], 0.f);
        float s = blockSum256(v, lds4);
        if (t == 0) fo[oc] = s * (1.f / 256.f);
    }
}

// ---- metric (mix fused: sets 2/3 from meanbuf; Sinkhorn dead code) ----
__global__ __launch_bounds__(128) void k_metric(const float* __restrict__ feats,
                                                const float* __restrict__ meanbuf,
                                                const float* __restrict__ PnT,
                                                const float* __restrict__ pn2,
                                                const int* __restrict__ la,
                                                const int* __restrict__ lb,
                                                float* __restrict__ mo) {
    __shared__ float lds2[2];
    __shared__ float xs[128];
    int blk = blockIdx.x;
    int t = threadIdx.x;
    int b = blk & 31;
    float xv;
    if (blk < 64) xv = feats[(size_t)blk * CI + t];
    else if (blk < 96) xv = LAMF * meanbuf[b * 128 + t] + ILAMF * meanbuf[12288 + b * 128 + t];
    else xv = LAMF * meanbuf[4096 + b * 128 + t] + ILAMF * meanbuf[8192 + b * 128 + t];
    float ssq = blockSum128(xv * xv, lds2);
    float sc = SCALEF / fmaxf(sqrtf(ssq), 1e-12f);
    float xn = xv * sc;
    xs[t] = xn;
    float xn2 = blockSum128(xn * xn, lds2);
    bool active = (t < NB);
    float Dk = 1e30f;
    if (active) {
        float dot = 0.f;
#pragma unroll 8
        for (int e = 0; e < CI; ++e) dot = fmaf(xs[e], PnT[e * NB + t], dot);
        Dk = xn2 + pn2[t] - 2.f * dot;
    }
    float z = active ? -Dk : -1e30f;
    float m = blockMax128(z, lds2);
    float e = active ? expf(z - m) : 0.f;
    float se = blockSum128(e, lds2);
    float lse = m + logf(se);
    if (t == 0) mo[blk * 3 + 0] = lse;
    int A = la[b], Bb = lb[b];
    if (t == A) mo[blk * 3 + 1] = Dk;
    if (t == Bb) mo[blk * 3 + 2] = Dk;
}

__global__ __launch_bounds__(128) void k_final(const float* __restrict__ pr,
                                               const float* __restrict__ mo,
                                               float* __restrict__ out) {
    __shared__ float mla[4], mlb[4];
    int t = threadIdx.x;
    const float* m = mo + t * 3;
    float ula = m[0] + m[1];
    float ulb = m[0] + m[2];
#pragma unroll
    for (int off = 16; off > 0; off >>= 1) {
        ula += __shfl_down(ula, off, 32);
        ulb += __shfl_down(ulb, off, 32);
    }
    if ((t & 31) == 0) { mla[t >> 5] = ula * (1.f / 32.f); mlb[t >> 5] = ulb * (1.f / 32.f); }
    __syncthreads();
    if (t == 0) {
        float lxa = pr[0] * (1.f / 4194304.f);
        float lxb = pr[1] * (1.f / 4194304.f);
        float lca = mla[0];
        float lcb = mlb[1];
        float lcma = LAMF * mla[2] + ILAMF * mlb[2];
        float lcmb = LAMF * mlb[3] + ILAMF * mla[3];
        out[0] = lxa + lxb + lca + lcb + lcma + lcmb;
        out[1] = lxa; out[2] = lxb; out[3] = lca; out[4] = lcb; out[5] = lcma; out[6] = lcmb;
    }
}

extern "C" void kernel_launch(void* const* d_in, const int* in_sizes, int n_in,
                              void* d_out, int out_size, void* d_ws, size_t ws_size,
                              hipStream_t stream) {
    const float* xa = (const float*)d_in[0];
    const float* xb = (const float*)d_in[1];
    const int* la = (const int*)d_in[2];
    const int* lb = (const int*)d_in[3];
    const float* P = (const float*)d_in[4];
    const float* We = (const float*)d_in[5];
    const float* Wf = (const float*)d_in[6];
    const float* Wd = (const float*)d_in[7];

    char* w = (char*)d_ws;
    const size_t XPAD_B = XSZ * 2 * sizeof(u16);
    const size_t CPAD_B = CSZ * 2 * sizeof(u16);
    const size_t AW_B = (size_t)294912 * 2;
    u16* xpad = (u16*)w;                 w += XPAD_B;
    u16* cpad = (u16*)w;                 w += CPAD_B;
    u16* A1p = (u16*)w;                  w += AW_B;
    u16* A2p = (u16*)w;                  w += AW_B;
    u16* A3p = (u16*)w;                  w += AW_B;
    float* PnT = (float*)w;              w += 12800 * 4;
    float* pn2 = (float*)w;              w += 128 * 4;
    float* feats = (float*)w;            w += 8192 * 4;    // [2 ab][32][128]
    float* meanbuf = (float*)w;          w += 16384 * 4;   // [2 kind][2 ab][32][128]
    float* pr = (float*)w;               w += 16 * 4;
    float* mo = (float*)w;               w += 384 * 4;
    float* pc0 = (float*)w;              w += (size_t)2 * 32 * 128 * 256 * 4;  // 8.4MB
    float* pc1 = (float*)w;              w += (size_t)2 * 32 * 128 * 256 * 4;  // 8.4MB
    float* out = (float*)d_out;

    // zero meanbuf + pr (atomically accumulated); feats/pc written fully
    hipMemsetAsync(meanbuf, 0, (16384 + 16) * sizeof(float), stream);

    k_prep_w<<<1152, 256, 0, stream>>>(We, Wf, Wd, A1p, A2p, A3p);
    k_prox<<<NB, 128, 0, stream>>>(P, PnT, pn2);
    k_ring<<<dim3(32, 2), 256, 0, stream>>>(xpad, cpad);
    k_xpose<<<dim3(32, 16, 2), 256, 0, stream>>>(xa, xb, xpad, meanbuf);
    k_conv1g<<<dim3(4, 32, 4), 256, 0, stream>>>(xpad, A1p, cpad);
    k_cde11<<<dim3(2, 32, 8), 256, 0, stream>>>(cpad, A2p, A3p, xpad, pc0, pc1, pr);
    k_cfin<<<dim3(8, 32, 2), 256, 0, stream>>>(pc0, pc1, feats);
    k_metric<<<128, 128, 0, stream>>>(feats, meanbuf, PnT, pn2, la, lb, mo);
    k_final<<<1, 128, 0, stream>>>(pr, mo, out);
}

// Round 17
// 99.848 us; speedup vs baseline: 1.2044x; 1.0378x over previous
//
#include <hip/hip_runtime.h>
#include <hip/hip_bf16.h>

#define DEVI __device__ __forceinline__

constexpr int B_ = 32, CI = 128, CM = 256, H_ = 32, W_ = 32;
constexpr int S_ = 1024, NB = 100;
constexpr float LAMF = 0.7f, ILAMF = 0.3f, SCALEF = 3.0f;
// chunked channel-last activation layouts: [b][ch/8][pos][8ch]
constexpr size_t XSZ = (size_t)32 * 16 * 1156 * 8;   // per-ab xpad elems (34x34 pos)
constexpr size_t XBS = (size_t)16 * 1156 * 8;        // per-b stride
constexpr size_t CSZ = (size_t)32 * 32 * 324 * 8;    // per-ab cpad elems (18x18 pos)
constexpr size_t CBS = (size_t)32 * 324 * 8;

typedef short bf8 __attribute__((ext_vector_type(8)));
typedef float f4 __attribute__((ext_vector_type(4)));
typedef float f16v __attribute__((ext_vector_type(16)));
typedef unsigned short u16;
typedef unsigned int u32;

struct alignas(8) us4 { u16 v[4]; };
struct alignas(16) us8 { u16 v[8]; };

// deconv tap order, parity-grouped: par0{0,2,6,8} par3{4} | par1{1,7} par2{3,5}
__device__ __constant__ int TAPD9c[9] = {0, 2, 6, 8, 1, 7, 3, 5, 4};

DEVI u16 f2bf(float f) {
    unsigned u = __builtin_bit_cast(unsigned, f);
    u += 0x7FFFu + ((u >> 16) & 1u);
    return (u16)(u >> 16);
}
DEVI float bf2f(u16 h) {
    unsigned u = ((unsigned)h) << 16;
    return __builtin_bit_cast(float, u);
}

DEVI void gll16(const void* g, void* l) {
    __builtin_amdgcn_global_load_lds(
        (const __attribute__((address_space(1))) u32*)g,
        (__attribute__((address_space(3))) u32*)l, 16, 0, 0);
}

DEVI float waveSum(float v) {
#pragma unroll
    for (int off = 32; off > 0; off >>= 1) v += __shfl_down(v, off, 64);
    return v;
}
DEVI float blockSum256(float v, float* lds4) {
    v = waveSum(v);
    int wid = threadIdx.x >> 6, lane = threadIdx.x & 63;
    __syncthreads();
    if (lane == 0) lds4[wid] = v;
    __syncthreads();
    return lds4[0] + lds4[1] + lds4[2] + lds4[3];
}
DEVI float blockSum128(float v, float* lds2) {
    v = waveSum(v);
    int wid = threadIdx.x >> 6, lane = threadIdx.x & 63;
    __syncthreads();
    if (lane == 0) lds2[wid] = v;
    __syncthreads();
    return lds2[0] + lds2[1];
}
DEVI float blockMax128(float v, float* lds2) {
#pragma unroll
    for (int off = 32; off > 0; off >>= 1) v = fmaxf(v, __shfl_down(v, off, 64));
    int wid = threadIdx.x >> 6, lane = threadIdx.x & 63;
    __syncthreads();
    if (lane == 0) lds2[wid] = v;
    __syncthreads();
    return fmaxf(lds2[0], lds2[1]);
}

// ---- weight prep: staging-linear k-slot-major layouts (unchanged from R8) ----
__global__ __launch_bounds__(256) void k_prep_w(const float* __restrict__ We,
                                                const float* __restrict__ Wf,
                                                const float* __restrict__ Wd,
                                                u16* __restrict__ A1p,
                                                u16* __restrict__ A2p,
                                                u16* __restrict__ A3p) {
    int i = blockIdx.x * 256 + threadIdx.x;  // 294912
    {
        int e = i & 7, s = (i >> 3) & 511, j = i >> 12;  // j 0..71
        int Mt = j / 36, kc = j - Mt * 36;
        int tap = kc >> 2, cq = kc & 3;
        int q = s >> 7, m = s & 127;
        int oc = Mt * 128 + m, ch = cq * 32 + q * 8 + e;
        A1p[i] = f2bf(We[((size_t)oc * CI + ch) * 9 + tap]);
    }
    {
        int e = i & 7, s = (i >> 3) & 511, kc = i >> 12;  // 0..71
        int tapi = kc >> 3, cq = kc & 7;
        int q = s >> 7, m = s & 127;
        int ch = cq * 32 + q * 8 + e;
        A2p[i] = f2bf(Wf[((size_t)m * CM + ch) * 9 + tapi]);
        A3p[i] = f2bf(Wd[((size_t)m * CM + ch) * 9 + TAPD9c[tapi]]);
    }
}

// ---- proxies ----
__global__ __launch_bounds__(128) void k_prox(const float* __restrict__ P,
                                              float* __restrict__ PnT,
                                              float* __restrict__ pn2) {
    __shared__ float lds2[2];
    int k = blockIdx.x, t = threadIdx.x;
    float v = P[k * CI + t];
    float ss = blockSum128(v * v, lds2);
    float sc = SCALEF / fmaxf(sqrtf(ss), 1e-12f);
    float pv = v * sc;
    PnT[t * NB + k] = pv;
    float s2 = blockSum128(pv * pv, lds2);
    if (t == 0) pn2[k] = s2;
}

// ---- zero the padding rings of xpad and cpad ----
__global__ __launch_bounds__(256) void k_ring(u16* __restrict__ xpad, u16* __restrict__ cpad) {
    int b = blockIdx.x, ab = blockIdx.y, t = threadIdx.x;
    u16* xp = xpad + (size_t)ab * XSZ + (size_t)b * XBS;
    u16* cp = cpad + (size_t)ab * CSZ + (size_t)b * CBS;
    us8 z = {};
    for (int i = t; i < 132 * 16; i += 256) {
        int cc = i / 132, rp = i - cc * 132;
        int pos;
        if (rp < 68) pos = (rp < 34) ? (32 * 34 + rp) : (33 * 34 + rp - 34);
        else { int r2 = rp - 68; pos = (r2 >> 1) * 34 + 32 + (r2 & 1); }
        *(us8*)(xp + ((size_t)cc * 1156 + pos) * 8) = z;
    }
    for (int i = t; i < 68 * 32; i += 256) {
        int cc = i / 68, rp = i - cc * 68;
        int pos;
        if (rp < 36) pos = (rp < 18) ? rp : (17 * 18 + rp - 18);
        else { int r2 = rp - 36; pos = (1 + (r2 >> 1)) * 18 + ((r2 & 1) ? 17 : 0); }
        *(us8*)(cp + ((size_t)cc * 324 + pos) * 8) = z;
    }
}

// ---- fused: x -> bf16 chunked xpad + invd (LDS-only) + mean PARTIALS (no atomics) ----
// mpart[kind2][ab2][b32][yg16][c128]; each slot written exactly once per call.
__global__ __launch_bounds__(256) void k_xpose(const float* __restrict__ xa,
                                               const float* __restrict__ xb,
                                               u16* __restrict__ xpad,
                                               float* __restrict__ mpart) {
    __shared__ float ldsx[128][64];   // 32KB
    __shared__ float sred[256];
    __shared__ float sinv[64];
    int b = blockIdx.x, yg = blockIdx.y, ab = blockIdx.z;
    int t = threadIdx.x;
    const float* x = (ab ? xb : xa) + (size_t)b * CI * S_ + yg * 64;
    int c4 = t >> 6, p = t & 63;
    for (int c0 = 0; c0 < 32; ++c0) {
        int c = c0 * 4 + c4;
        ldsx[c][p] = x[(size_t)c * S_ + p];
    }
    __syncthreads();
    int qc = t >> 6;
    int y = yg * 2 + (p >> 5), xcol = p & 31;
    u16* ox = xpad + (size_t)ab * XSZ + (size_t)b * XBS;
    float ss = 0.f;
#pragma unroll
    for (int c8 = 0; c8 < 4; ++c8) {
        int cb = qc * 32 + c8 * 8;
        int cc = cb >> 3;
        us8 pk;
#pragma unroll
        for (int j = 0; j < 8; ++j) {
            float v = ldsx[cb + j][p];
            ss = fmaf(v, v, ss);
            pk.v[j] = f2bf(v);
        }
        *(us8*)(ox + ((size_t)cc * 1156 + y * 34 + xcol) * 8) = pk;
    }
    sred[t] = ss;
    __syncthreads();
    if (t < 64) {
        float s = sred[t] + sred[t + 64] + sred[t + 128] + sred[t + 192];
        sinv[t] = 1.f / fmaxf(sqrtf(s), 1e-12f);
    }
    __syncthreads();
    int c = t >> 1, h = t & 1;
    float sx = 0.f, sf = 0.f;
    for (int i = 0; i < 32; ++i) {
        int p2 = h * 32 + ((i + c) & 31);
        float v = ldsx[c][p2];
        sx += v;
        sf = fmaf(v, sinv[p2], sf);
    }
    sx += __shfl_xor(sx, 1, 64);
    sf += __shfl_xor(sf, 1, 64);
    if (!(t & 1)) {
        size_t base = ((size_t)(ab * 32 + b) * 16 + yg) * 128 + c;
        mpart[base] = sx * (1.f / 1024.f);                      // kind 0: meanx
        mpart[(size_t)2 * 32 * 16 * 128 * 2 / 2 + base] = sf * (1.f / 1024.f);  // kind 1
    }
}

// ---- conv1: K-64 steps (18), tile M128 x N64, LDS dbuf (unchanged from R8) ----
__global__ __launch_bounds__(256, 2) void k_conv1g(const u16* __restrict__ XC,
                                                   const u16* __restrict__ A1p,
                                                   u16* __restrict__ CC) {
    __shared__ u16 sA[2][8192];
    __shared__ u16 sB[2][4096];
    int t = threadIdx.x, l = t & 63, l15 = l & 15, lq = l >> 4, w = t >> 6;
    int wm = w & 1, wn = w >> 1;
    int Nt = blockIdx.x, b = blockIdx.y;
    int ab = blockIdx.z & 1, Mt = blockIdx.z >> 1;
    const u16* xc = XC + (size_t)ab * XSZ + (size_t)b * XBS;
    const u16* Ag = A1p + (size_t)Mt * (36 * 4096);
    int bpos0 = (8 * Nt + 2 * (l >> 4)) * 34 + 2 * (l & 15);
    const int po1[9] = {0, 1, 2, 34, 35, 36, 68, 69, 70};

    auto stageA = [&](int buf, int kcA) {
        const u16* ga = Ag + (size_t)kcA * 4096 + t * 8;
        u16* da = &sA[buf][w * 512];
#pragma unroll
        for (int i = 0; i < 4; ++i) gll16(ga + i * 2048, da + i * 2048);
    };
    auto stageB = [&](int buf, int po, int s) {
#pragma unroll
        for (int i = 0; i < 2; ++i) {
            int ks = i * 4 + w;
            gll16(xc + ((size_t)(s * 8 + ks) * 1156 + bpos0 + po) * 8,
                  &sB[buf][(size_t)ks * 512]);
        }
    };

    f4 acc[4][2] = {};
    stageA(0, 0);
    stageB(0, 0, 0);
    int cur = 0;
#pragma unroll
    for (int ti = 0; ti < 9; ++ti) {
        const int po = po1[ti];
        const int poN = (ti < 8) ? po1[ti + 1] : 0;
#pragma unroll 1
        for (int s = 0; s < 2; ++s) {
            __syncthreads();
            bool last = (ti == 8) && (s == 1);
            if (!last) {
                int tin = (s < 1) ? ti : ti + 1;
                int sn = (s < 1) ? 1 : 0;
                stageA(cur ^ 1, tin * 4 + sn * 2);
                stageB(cur ^ 1, (s < 1) ? po : poN, sn);
            }
            const u16* As = sA[cur];
            const u16* Bs = sB[cur];
#pragma unroll
            for (int kc2 = 0; kc2 < 2; ++kc2) {
                bf8 af[4], bv[2];
#pragma unroll
                for (int mf = 0; mf < 4; ++mf)
                    af[mf] = *(const bf8*)(As + ((kc2 * 4 + lq) * 128 + wm * 64 + mf * 16 + l15) * 8);
#pragma unroll
                for (int nf = 0; nf < 2; ++nf)
                    bv[nf] = *(const bf8*)(Bs + ((kc2 * 4 + lq) * 64 + wn * 32 + nf * 16 + l15) * 8);
#pragma unroll
                for (int mf = 0; mf < 4; ++mf)
#pragma unroll
                    for (int nf = 0; nf < 2; ++nf)
                        acc[mf][nf] = __builtin_amdgcn_mfma_f32_16x16x32_bf16(af[mf], bv[nf], acc[mf][nf], 0, 0, 0);
            }
            cur ^= 1;
        }
    }
    u16* cb = CC + (size_t)ab * CSZ + (size_t)b * CBS;
#pragma unroll
    for (int mf = 0; mf < 4; ++mf) {
        int mc = Mt * 128 + wm * 64 + mf * 16 + lq * 4;
#pragma unroll
        for (int nf = 0; nf < 2; ++nf) {
            int nl = wn * 32 + nf * 16 + l15;
            int oh = Nt * 4 + (nl >> 4), ow = nl & 15;
            int posO = (1 + oh) * 18 + 1 + ow;
            us4 pk;
#pragma unroll
            for (int r = 0; r < 4; ++r) pk.v[r] = f2bf(fmaxf(acc[mf][nf][r], 0.f));
            *(us4*)(cb + ((size_t)(mc >> 3) * 324 + posO) * 8 + (mc & 7)) = pk;
        }
    }
}

// ---- k_cde11: 512 balanced blocks (~18 steps each), R14 skeleton ----
// units: u0 conv2 ch 0..127 -> pc0 (18 steps), u1 conv2 ch 128..255 -> pc1 (18),
// u2 deconv par{0,3} (20), u3 deconv par{1,2} (16). grid (2 Nt, 32 b, 8: unit*2+ab)
// Deconv MSE -> per-block slot prpart[ab*128 + ((unit-2)*2+Nt)*32+b] (no atomics).

#define KSTEP(ACC, KYV, KXV, HN, KCAN)                                              \
    {                                                                               \
        __syncthreads();                                                            \
        if (HN) stageA(cur ^ 1, (KCAN));                                            \
        const u16* As = sA[cur];                                                    \
        _Pragma("unroll") for (int kc2 = 0; kc2 < 2; ++kc2) {                       \
            _Pragma("unroll") for (int j = 0; j < 2; ++j) {                         \
                bf8 a0 = *(const bf8*)(As + kc2 * 4096 + j * 2048 + aBase);         \
                bf8 a1 = *(const bf8*)(As + kc2 * 4096 + j * 2048 + aBase + 256);   \
                const u16* bp = sS + (kc2 * 720 + j * 360) * 8 + bBase;             \
                bf8 b0 = *(const bf8*)(bp + (((KYV)) * 18 + (KXV)) * 8);            \
                bf8 b1 = *(const bf8*)(bp + (((KYV) + 2) * 18 + (KXV)) * 8);        \
                ACC[0][0] = __builtin_amdgcn_mfma_f32_32x32x16_bf16(a0, b0, ACC[0][0], 0, 0, 0); \
                ACC[0][1] = __builtin_amdgcn_mfma_f32_32x32x16_bf16(a0, b1, ACC[0][1], 0, 0, 0); \
                ACC[1][0] = __builtin_amdgcn_mfma_f32_32x32x16_bf16(a1, b0, ACC[1][0], 0, 0, 0); \
                ACC[1][1] = __builtin_amdgcn_mfma_f32_32x32x16_bf16(a1, b1, ACC[1][1], 0, 0, 0); \
            }                                                                       \
        }                                                                           \
        cur ^= 1;                                                                   \
    }

#define FLUSH(ACC, PY, PX)                                                          \
    _Pragma("unroll") for (int mf = 0; mf < 2; ++mf) {                              \
        _Pragma("unroll") for (int nf = 0; nf < 2; ++nf) {                          \
            int n = wn * 64 + nf * 32 + l31;                                        \
            int oh = 8 * Nt + (n >> 4), ow = n & 15;                                \
            int Y = 2 * oh + (PY), X = 2 * ow + (PX);                               \
            _Pragma("unroll") for (int rg = 0; rg < 4; ++rg) {                      \
                int mc = wm * 64 + mf * 32 + 8 * rg + 4 * lh;                       \
                us4 xv = *(const us4*)(xq + (size_t)(mc >> 3) * 1156 * 8 +          \
                                       (size_t)(Y * 34 + X) * 8 + (mc & 7));        \
                _Pragma("unroll") for (int r = 0; r < 4; ++r) {                     \
                    float d = ACC[mf][nf][rg * 4 + r] - bf2f(xv.v[r]);              \
                    ss = fmaf(d, d, ss);                                            \
                }                                                                   \
            }                                                                       \
        }                                                                           \
    }

__global__ __launch_bounds__(256, 2) void k_cde11(const u16* __restrict__ CC,
                                                  const u16* __restrict__ A2p,
                                                  const u16* __restrict__ A3p,
                                                  const u16* __restrict__ XC,
                                                  float* __restrict__ pc0,
                                                  float* __restrict__ pc1,
                                                  float* __restrict__ prpart) {
    __shared__ u16 sS[11520];     // [ccL8][pos 10x18][8e] = 22.5KB (one 32-ch seg)
    __shared__ u16 sA[2][8192];   // A dbuf 2x16KB
    __shared__ float lds4[4];
    int t = threadIdx.x, l = t & 63, l31 = l & 31, lh = l >> 5, w = t >> 6;
    int wm = w & 1, wn = w >> 1;
    int Nt = blockIdx.x, b = blockIdx.y;
    int ab = blockIdx.z & 1, unit = blockIdx.z >> 1;
    const u16* cbb = CC + (size_t)ab * CSZ + (size_t)b * CBS;
    const u16* xq = XC + (size_t)ab * XSZ + (size_t)b * XBS;
    const u16* Ag = (unit < 2) ? A2p : A3p;
    int r0 = 8 * Nt;
    int aBase = (lh * 128 + wm * 64 + l31) * 8;
    int bBase = (lh * 180 + (wn * 4 + (l31 >> 4)) * 18 + (l31 & 15)) * 8;

    auto stageA = [&](int buf, int kcA) {   // 2 chunks = 16KB contiguous
        const u16* ga = Ag + (size_t)kcA * 4096 + t * 8;
        u16* da = &sA[buf][w * 512];
#pragma unroll
        for (int i = 0; i < 4; ++i) gll16(ga + i * 2048, da + i * 2048);
    };
    auto stage_slab = [&](int seg) {        // 8 chunks of the 32-ch seg slice
        if (t < 180) {
            int cc0 = (seg >> 1) * 16 + (seg & 1) * 8;
#pragma unroll 1
            for (int ccL = 0; ccL < 8; ++ccL) {
                us8 v = *(const us8*)(cbb + ((size_t)(cc0 + ccL) * 324 + r0 * 18 + t) * 8);
                *(us8*)(sS + ((size_t)ccL * 180 + t) * 8) = v;
            }
        }
    };

    int cur = 0;
    float ss = 0.f;
    if (unit < 2) {
        // conv2 channel-half: segs {2*unit, 2*unit+1}, 18 steps -> raw partial
        f16v acc[2][2] = {};
        int segBase = unit * 2;
        stage_slab(segBase);
        stageA(0, (segBase >> 1) * 4 + (segBase & 1) * 2);
#pragma unroll
        for (int sl = 0; sl < 2; ++sl) {
            int seg = segBase + sl;
            if (sl) { __syncthreads(); stage_slab(seg); }
#pragma unroll 1
            for (int tap = 0; tap < 9; ++tap) {
                int s = sl * 9 + tap;
                int ky = tap / 3, kx = tap - ky * 3;
                bool hn = s < 17;
                int s1 = hn ? s + 1 : 0;
                int sl1 = s1 / 9, tap1 = s1 - sl1 * 9;
                int seg1 = segBase + sl1;
                int kcan = tap1 * 8 + (seg1 >> 1) * 4 + (seg1 & 1) * 2;
                KSTEP(acc, ky, kx, hn, kcan);
            }
        }
        float* pw = (unit == 0 ? pc0 : pc1) + (size_t)(ab * 32 + b) * 128 * 256;
#pragma unroll
        for (int mf = 0; mf < 2; ++mf)
#pragma unroll
            for (int nf = 0; nf < 2; ++nf)
#pragma unroll
                for (int reg = 0; reg < 16; ++reg) {
                    int oc = wm * 64 + mf * 32 + (reg & 3) + 8 * (reg >> 2) + 4 * lh;
                    int pos = 128 * Nt + wn * 64 + nf * 32 + l31;
                    pw[(size_t)oc * 256 + pos] = acc[mf][nf][reg];
                }
    } else if (unit == 2) {
        // deconv par{0,3}: 20 steps = seg(4) x r(5)
        f16v accP[2][2] = {}, accQ[2][2] = {};
        stage_slab(0);
        stageA(0, 0);
#pragma unroll
        for (int seg = 0; seg < 4; ++seg) {
            if (seg) { __syncthreads(); stage_slab(seg); }
#pragma unroll 1
            for (int r = 0; r < 5; ++r) {
                int s = seg * 5 + r;
                bool hn = s < 19;
                int s1 = hn ? s + 1 : 0;
                int seg1 = s1 / 5, r1 = s1 - seg1 * 5;
                int tapi1 = (r1 < 4) ? r1 : 8;
                int kcan = tapi1 * 8 + (seg1 >> 1) * 4 + (seg1 & 1) * 2;
                if (r < 4) {
                    int dy = r >> 1, dx = r & 1;
                    KSTEP(accP, dy, dx, hn, kcan);
                } else {
                    KSTEP(accQ, 1, 1, hn, kcan);
                }
            }
        }
        FLUSH(accP, 0, 0);
        FLUSH(accQ, 1, 1);
        ss = blockSum256(ss, lds4);
        if (t == 0) prpart[ab * 128 + Nt * 32 + b] = ss;
    } else {
        // deconv par{1,2}: 16 steps = seg(4) x r(4)
        f16v accP[2][2] = {}, accQ[2][2] = {};
        stage_slab(0);
        stageA(0, 32);
#pragma unroll
        for (int seg = 0; seg < 4; ++seg) {
            if (seg) { __syncthreads(); stage_slab(seg); }
#pragma unroll 1
            for (int r = 0; r < 4; ++r) {
                int s = seg * 4 + r;
                bool hn = s < 15;
                int s1 = hn ? s + 1 : 0;
                int seg1 = s1 >> 2, r1 = s1 & 3;
                int kcan = (4 + r1) * 8 + (seg1 >> 1) * 4 + (seg1 & 1) * 2;
                if (r < 2) {
                    KSTEP(accP, r, 1, hn, kcan);
                } else {
                    KSTEP(accQ, 1, r - 2, hn, kcan);
                }
            }
        }
        FLUSH(accP, 0, 1);
        FLUSH(accQ, 1, 0);
        ss = blockSum256(ss, lds4);
        if (t == 0) prpart[ab * 128 + 64 + Nt * 32 + b] = ss;
    }
}

#undef KSTEP
#undef FLUSH

// ---- conv2 epilogue: feats = mean(relu(pc0 + pc1)) ----
__global__ __launch_bounds__(256) void k_cfin(const float* __restrict__ pc0,
                                              const float* __restrict__ pc1,
                                              float* __restrict__ feats) {
    __shared__ float lds4[4];
    int ocg = blockIdx.x, b = blockIdx.y, ab = blockIdx.z;
    int t = threadIdx.x;
    const float* p0 = pc0 + (size_t)(ab * 32 + b) * 128 * 256;
    const float* p1 = pc1 + (size_t)(ab * 32 + b) * 128 * 256;
    float* fo = feats + (size_t)(ab * 32 + b) * 128;
#pragma unroll 1
    for (int i = 0; i < 16; ++i) {
        int oc = ocg * 16 + i;
        float v = fmaxf(p0[(size_t)oc * 256 + t] + p1[(size_t)oc * 256 + t], 0.f);
        float s = blockSum256(v, lds4);
        if (t == 0) fo[oc] = s * (1.f / 256.f);
    }
}

// ---- metric (mix fused: sets 2/3 summed from mpart partials) ----
constexpr size_t MPK = (size_t)2 * 32 * 16 * 128;   // per-kind stride in mpart

__global__ __launch_bounds__(128) void k_metric(const float* __restrict__ feats,
                                                const float* __restrict__ mpart,
                                                const float* __restrict__ PnT,
                                                const float* __restrict__ pn2,
                                                const int* __restrict__ la,
                                                const int* __restrict__ lb,
                                                float* __restrict__ mo) {
    __shared__ float lds2[2];
    __shared__ float xs[128];
    int blk = blockIdx.x;
    int t = threadIdx.x;
    int b = blk & 31;
    float xv;
    if (blk < 64) {
        xv = feats[(size_t)blk * CI + t];
    } else {
        // set2 (blk<96): lam*meanx_a + (1-lam)*meanfl_b ; set3: lam*meanx_b + (1-lam)*meanfl_a
        int abx = (blk < 96) ? 0 : 1;
        int abf = 1 - abx;
        const float* mx = mpart + ((size_t)(abx * 32 + b) * 16) * 128 + t;
        const float* mf = mpart + MPK + ((size_t)(abf * 32 + b) * 16) * 128 + t;
        float s = 0.f;
#pragma unroll
        for (int yg = 0; yg < 16; ++yg)
            s += LAMF * mx[yg * 128] + ILAMF * mf[yg * 128];
        xv = s;
    }
    float ssq = blockSum128(xv * xv, lds2);
    float sc = SCALEF / fmaxf(sqrtf(ssq), 1e-12f);
    float xn = xv * sc;
    xs[t] = xn;
    float xn2 = blockSum128(xn * xn, lds2);
    bool active = (t < NB);
    float Dk = 1e30f;
    if (active) {
        float dot = 0.f;
#pragma unroll 8
        for (int e = 0; e < CI; ++e) dot = fmaf(xs[e], PnT[e * NB + t], dot);
        Dk = xn2 + pn2[t] - 2.f * dot;
    }
    float z = active ? -Dk : -1e30f;
    float m = blockMax128(z, lds2);
    float e = active ? expf(z - m) : 0.f;
    float se = blockSum128(e, lds2);
    float lse = m + logf(se);
    if (t == 0) mo[blk * 3 + 0] = lse;
    int A = la[b], Bb = lb[b];
    if (t == A) mo[blk * 3 + 1] = Dk;
    if (t == Bb) mo[blk * 3 + 2] = Dk;
}

__global__ __launch_bounds__(128) void k_final(const float* __restrict__ prpart,
                                               const float* __restrict__ mo,
                                               float* __restrict__ out) {
    __shared__ float lds2[2];
    __shared__ float mla[4], mlb[4];
    int t = threadIdx.x;
    float sa = blockSum128(prpart[t], lds2);
    float sb = blockSum128(prpart[128 + t], lds2);
    const float* m = mo + t * 3;
    float ula = m[0] + m[1];
    float ulb = m[0] + m[2];
#pragma unroll
    for (int off = 16; off > 0; off >>= 1) {
        ula += __shfl_down(ula, off, 32);
        ulb += __shfl_down(ulb, off, 32);
    }
    if ((t & 31) == 0) { mla[t >> 5] = ula * (1.f / 32.f); mlb[t >> 5] = ulb * (1.f / 32.f); }
    __syncthreads();
    if (t == 0) {
        float lxa = sa * (1.f / 4194304.f);
        float lxb = sb * (1.f / 4194304.f);
        float lca = mla[0];
        float lcb = mlb[1];
        float lcma = LAMF * mla[2] + ILAMF * mlb[2];
        float lcmb = LAMF * mlb[3] + ILAMF * mla[3];
        out[0] = lxa + lxb + lca + lcb + lcma + lcmb;
        out[1] = lxa; out[2] = lxb; out[3] = lca; out[4] = lcb; out[5] = lcma; out[6] = lcmb;
    }
}

extern "C" void kernel_launch(void* const* d_in, const int* in_sizes, int n_in,
                              void* d_out, int out_size, void* d_ws, size_t ws_size,
                              hipStream_t stream) {
    const float* xa = (const float*)d_in[0];
    const float* xb = (const float*)d_in[1];
    const int* la = (const int*)d_in[2];
    const int* lb = (const int*)d_in[3];
    const float* P = (const float*)d_in[4];
    const float* We = (const float*)d_in[5];
    const float* Wf = (const float*)d_in[6];
    const float* Wd = (const float*)d_in[7];

    char* w = (char*)d_ws;
    const size_t XPAD_B = XSZ * 2 * sizeof(u16);
    const size_t CPAD_B = CSZ * 2 * sizeof(u16);
    const size_t AW_B = (size_t)294912 * 2;
    u16* xpad = (u16*)w;                 w += XPAD_B;
    u16* cpad = (u16*)w;                 w += CPAD_B;
    u16* A1p = (u16*)w;                  w += AW_B;
    u16* A2p = (u16*)w;                  w += AW_B;
    u16* A3p = (u16*)w;                  w += AW_B;
    float* PnT = (float*)w;              w += 12800 * 4;
    float* pn2 = (float*)w;              w += 128 * 4;
    float* feats = (float*)w;            w += 8192 * 4;    // [2 ab][32][128]
    float* mpart = (float*)w;            w += MPK * 2 * 4; // 1MB mean partials
    float* prpart = (float*)w;           w += 256 * 4;
    float* mo = (float*)w;               w += 384 * 4;
    float* pc0 = (float*)w;              w += (size_t)2 * 32 * 128 * 256 * 4;  // 8.4MB
    float* pc1 = (float*)w;              w += (size_t)2 * 32 * 128 * 256 * 4;  // 8.4MB
    float* out = (float*)d_out;

    // No memset: every consumed slot is written unconditionally each call.
    k_prep_w<<<1152, 256, 0, stream>>>(We, Wf, Wd, A1p, A2p, A3p);
    k_prox<<<NB, 128, 0, stream>>>(P, PnT, pn2);
    k_ring<<<dim3(32, 2), 256, 0, stream>>>(xpad, cpad);
    k_xpose<<<dim3(32, 16, 2), 256, 0, stream>>>(xa, xb, xpad, mpart);
    k_conv1g<<<dim3(4, 32, 4), 256, 0, stream>>>(xpad, A1p, cpad);
    k_cde11<<<dim3(2, 32, 8), 256, 0, stream>>>(cpad, A2p, A3p, xpad, pc0, pc1, prpart);
    k_cfin<<<dim3(8, 32, 2), 256, 0, stream>>>(pc0, pc1, feats);
    k_metric<<<128, 128, 0, stream>>>(feats, mpart, PnT, pn2, la, lb, mo);
    k_final<<<1, 128, 0, stream>>>(prpart, mo, out);
}